// Round 2
// baseline (234.174 us; speedup 1.0000x reference)
//
#include <hip/hip_runtime.h>
#include <hip/hip_bf16.h>
#include <stdint.h>

#define S_LEN  2048
#define DMODEL 1024
#define NHEADS 16
#define HDIM   64

typedef __attribute__((ext_vector_type(8))) _Float16 half8;
typedef __attribute__((ext_vector_type(4))) float    f32x4;

// ---------------- fp32 -> fp16 convert ----------------
struct CvtArgs {
    const float* src[7];
    _Float16*    dst[7];
    int          n[7];
};

__global__ __launch_bounds__(256) void cvt_kernel(CvtArgs a) {
    const int z = blockIdx.z;
    const float* __restrict__ src = a.src[z];
    _Float16* __restrict__ dst = a.dst[z];
    const int n = a.n[z];
    const int stride = gridDim.x * blockDim.x * 8;
    for (int i = (blockIdx.x * blockDim.x + threadIdx.x) * 8; i < n; i += stride) {
        float4 v0 = *(const float4*)(src + i);
        float4 v1 = *(const float4*)(src + i + 4);
        half8 o;
        o[0] = (_Float16)v0.x; o[1] = (_Float16)v0.y;
        o[2] = (_Float16)v0.z; o[3] = (_Float16)v0.w;
        o[4] = (_Float16)v1.x; o[5] = (_Float16)v1.y;
        o[6] = (_Float16)v1.z; o[7] = (_Float16)v1.w;
        *(half8*)(dst + i) = o;
    }
}

// ---------------- GEMM: C[M=2048][N=1024] = A[2048][1024] x W[1024][1024]^T + bias ----------------
// Tile: BM=64, BN=128, BK=32. 256 threads = 4 waves in 2x2, each wave 32x64 (2x4 MFMA frags).
__device__ __forceinline__ void gload16(const _Float16* g, _Float16* l) {
    __builtin_amdgcn_global_load_lds(
        (__attribute__((address_space(1))) void*)const_cast<_Float16*>(g),
        (__attribute__((address_space(3))) void*)l, 16, 0, 0);
}

template<typename OT>
__device__ __forceinline__ void gemm_body(
    const _Float16* __restrict__ A,
    const _Float16* __restrict__ W,
    const float*    __restrict__ bias,
    OT* __restrict__ C, float scale)
{
    __shared__ _Float16 As[64 * 32];   // linear (global_load_lds needs contiguous dest)
    __shared__ _Float16 Bs[128 * 32];
    const int tid  = threadIdx.x;
    const int lane = tid & 63, wid = tid >> 6;
    const int row0 = blockIdx.y * 64;
    const int col0 = blockIdx.x * 128;
    const int wr = wid >> 1, wc = wid & 1;
    const int lr = lane & 15, lg = lane >> 4;

    f32x4 acc[2][4];
#pragma unroll
    for (int i = 0; i < 2; i++)
#pragma unroll
        for (int j = 0; j < 4; j++) acc[i][j] = (f32x4)(0.0f);

    for (int k0 = 0; k0 < DMODEL; k0 += 32) {
        {   // stage A: 256 granules of 16B, one per thread; wave-uniform LDS base + lane*16
            const int g = wid * 64 + lane;
            gload16(A + (size_t)(row0 + (g >> 2)) * DMODEL + k0 + (g & 3) * 8,
                    As + (size_t)wid * 64 * 8);
        }
#pragma unroll
        for (int r = 0; r < 2; r++) {   // stage B: 512 granules
            const int g = r * 256 + wid * 64 + lane;
            gload16(W + (size_t)(col0 + (g >> 2)) * DMODEL + k0 + (g & 3) * 8,
                    Bs + ((size_t)r * 256 + wid * 64) * 8);
        }
        __syncthreads();
        half8 af[2], bfr[4];
#pragma unroll
        for (int i = 0; i < 2; i++)
            af[i] = *(const half8*)(As + (wr * 32 + i * 16 + lr) * 32 + lg * 8);
#pragma unroll
        for (int j = 0; j < 4; j++)
            bfr[j] = *(const half8*)(Bs + (wc * 64 + j * 16 + lr) * 32 + lg * 8);
#pragma unroll
        for (int i = 0; i < 2; i++)
#pragma unroll
            for (int j = 0; j < 4; j++)
                acc[i][j] = __builtin_amdgcn_mfma_f32_16x16x32_f16(af[i], bfr[j], acc[i][j], 0, 0, 0);
        __syncthreads();
    }
    // epilogue: C/D layout col=lane&15, row=(lane>>4)*4+reg
#pragma unroll
    for (int i = 0; i < 2; i++)
#pragma unroll
        for (int j = 0; j < 4; j++) {
            const int row = row0 + wr * 32 + i * 16 + lg * 4;
            const int col = col0 + wc * 64 + j * 16 + lr;
            const float b = bias[col];
#pragma unroll
            for (int rj = 0; rj < 4; rj++) {
                float v = (acc[i][j][rj] + b) * scale;
                if constexpr (sizeof(OT) == 2)
                    C[(size_t)(row + rj) * DMODEL + col] = (OT)(_Float16)v;
                else
                    C[(size_t)(row + rj) * DMODEL + col] = v;
            }
        }
}

struct QKVArgs {
    const _Float16* A[3];
    const _Float16* W[3];
    const float*    bias[3];
    _Float16*       C[3];
    float           scale[3];
};

__global__ __launch_bounds__(256) void gemm_qkv(QKVArgs a) {
    const int z = blockIdx.z;
    gemm_body<_Float16>(a.A[z], a.W[z], a.bias[z], a.C[z], a.scale[z]);
}

__global__ __launch_bounds__(256) void gemm_out_k(const _Float16* __restrict__ A,
                                                  const _Float16* __restrict__ W,
                                                  const float* __restrict__ bias,
                                                  float* __restrict__ C) {
    gemm_body<float>(A, W, bias, C, 1.0f);
}

// ---------------- V transpose: v[2048][1024] -> Vt[16][64][2048] ----------------
__global__ __launch_bounds__(256) void transpose_v(const _Float16* __restrict__ v,
                                                   _Float16* __restrict__ Vt) {
    __shared__ _Float16 t[64][72];   // pad 8 halves (16B) keeps alignment, breaks conflicts
    const int s0 = blockIdx.x * 64;
    const int h  = blockIdx.y;
    const int tid = threadIdx.x;
#pragma unroll
    for (int r = 0; r < 2; r++) {
        const int g = r * 256 + tid;
        const int sr = g >> 3, c8 = (g & 7) * 8;
        *(half8*)(&t[sr][c8]) = *(const half8*)(v + (size_t)(s0 + sr) * DMODEL + h * HDIM + c8);
    }
    __syncthreads();
#pragma unroll
    for (int r = 0; r < 2; r++) {
        const int g = r * 256 + tid;
        const int d = g >> 3, c8 = (g & 7) * 8;
        half8 o;
#pragma unroll
        for (int j = 0; j < 8; j++) o[j] = t[c8 + j][d];
        *(half8*)(Vt + (size_t)(h * HDIM + d) * S_LEN + s0 + c8) = o;
    }
}

// ---------------- causal flash attention ----------------
// grid: (32 q-tiles [reversed], 16 heads), 256 thr = 4 waves, wave handles 16 q rows.
// q pre-scaled by 1/8. K read from global (L2-resident), V via Vt (pre-transposed).
__global__ __launch_bounds__(256) void attn_kernel(
    const _Float16* __restrict__ q,
    const _Float16* __restrict__ k,
    const _Float16* __restrict__ Vt,
    _Float16* __restrict__ o)
{
    __shared__ _Float16 P[4][16][72];   // per-wave P tile, stride 144B (16B aligned, 2-way banks)
    const int tid = threadIdx.x, lane = tid & 63, wid = tid >> 6;
    const int qt = (int)gridDim.x - 1 - (int)blockIdx.x;   // heavy tiles first
    const int h  = blockIdx.y;
    const int q0 = qt * 64 + wid * 16;
    const int lr = lane & 15, lg = lane >> 4;

    half8 qf[2];
#pragma unroll
    for (int ds = 0; ds < 2; ds++)
        qf[ds] = *(const half8*)(q + (size_t)(q0 + lr) * DMODEL + h * HDIM + ds * 32 + lg * 8);

    float m[4], lsum[4];
    f32x4 od[4];
#pragma unroll
    for (int r = 0; r < 4; r++) { m[r] = -1e30f; lsum[r] = 0.0f; }
#pragma unroll
    for (int dt = 0; dt < 4; dt++) od[dt] = (f32x4)(0.0f);

    const int nsteps = qt + 1;
    for (int step = 0; step < nsteps; step++) {
        const int k0 = step * 64;
        f32x4 sc[4];
#pragma unroll
        for (int kt = 0; kt < 4; kt++) {
            sc[kt] = (f32x4)(0.0f);
#pragma unroll
            for (int ds = 0; ds < 2; ds++) {
                half8 kf = *(const half8*)(k + (size_t)(k0 + kt * 16 + lr) * DMODEL + h * HDIM + ds * 32 + lg * 8);
                sc[kt] = __builtin_amdgcn_mfma_f32_16x16x32_f16(qf[ds], kf, sc[kt], 0, 0, 0);
            }
        }
        // Diagonal step: causal mask. Trigger when ANY key in this step can
        // exceed the wave's MIN row (k0+63 > q0) — comparing against the max
        // row (q0+15) wrongly skips wave 3, whose qmax == k0+63. (R1 fix)
        if (k0 + 63 > q0) {
#pragma unroll
            for (int kt = 0; kt < 4; kt++) {
                const int kk = k0 + kt * 16 + lr;
#pragma unroll
                for (int r = 0; r < 4; r++)
                    if (kk > q0 + lg * 4 + r) sc[kt][r] = -1e30f;
            }
        }
        // online softmax; row reduce over 16 lanes (same lg group)
#pragma unroll
        for (int r = 0; r < 4; r++) {
            float vmax = sc[0][r];
#pragma unroll
            for (int kt = 1; kt < 4; kt++) vmax = fmaxf(vmax, sc[kt][r]);
#pragma unroll
            for (int off = 1; off < 16; off <<= 1) vmax = fmaxf(vmax, __shfl_xor(vmax, off));
            const float mnew = fmaxf(m[r], vmax);
            const float sfac = __expf(m[r] - mnew);
            float psum = 0.0f;
#pragma unroll
            for (int kt = 0; kt < 4; kt++) {
                const float p = __expf(sc[kt][r] - mnew);
                sc[kt][r] = p;
                psum += p;
            }
#pragma unroll
            for (int off = 1; off < 16; off <<= 1) psum += __shfl_xor(psum, off);
            lsum[r] = lsum[r] * sfac + psum;
            m[r] = mnew;
#pragma unroll
            for (int dt = 0; dt < 4; dt++) od[dt][r] *= sfac;
        }
        // P (C-layout) -> LDS, re-read as A-fragments
#pragma unroll
        for (int kt = 0; kt < 4; kt++)
#pragma unroll
            for (int r = 0; r < 4; r++)
                P[wid][lg * 4 + r][kt * 16 + lr] = (_Float16)sc[kt][r];
#pragma unroll
        for (int ks = 0; ks < 2; ks++) {
            half8 pa = *(const half8*)(&P[wid][lr][ks * 32 + lg * 8]);
#pragma unroll
            for (int dt = 0; dt < 4; dt++) {
                half8 vb = *(const half8*)(Vt + (size_t)(h * HDIM + dt * 16 + lr) * S_LEN + k0 + ks * 32 + lg * 8);
                od[dt] = __builtin_amdgcn_mfma_f32_16x16x32_f16(pa, vb, od[dt], 0, 0, 0);
            }
        }
    }
#pragma unroll
    for (int dt = 0; dt < 4; dt++) {
        const int d = h * HDIM + dt * 16 + lr;
#pragma unroll
        for (int r = 0; r < 4; r++) {
            const float v = od[dt][r] / lsum[r];
            o[(size_t)(q0 + lg * 4 + r) * DMODEL + d] = (_Float16)v;
        }
    }
}

// ---------------- launch ----------------
extern "C" void kernel_launch(void* const* d_in, const int* in_sizes, int n_in,
                              void* d_out, int out_size, void* d_ws, size_t ws_size,
                              hipStream_t stream) {
    const float* Q  = (const float*)d_in[0];
    const float* K  = (const float*)d_in[1];
    const float* V  = (const float*)d_in[2];
    const float* Wq = (const float*)d_in[3];
    const float* bq = (const float*)d_in[4];
    const float* Wk = (const float*)d_in[5];
    const float* bk = (const float*)d_in[6];
    const float* Wv = (const float*)d_in[7];
    const float* bv = (const float*)d_in[8];
    const float* Wo = (const float*)d_in[9];
    const float* bo = (const float*)d_in[10];

    _Float16* ws = (_Float16*)d_ws;
    const size_t SD = (size_t)S_LEN * DMODEL;   // 2M
    const size_t WD = (size_t)DMODEL * DMODEL;  // 1M
    _Float16* Qh  = ws;
    _Float16* Kh  = Qh + SD;
    _Float16* Vh  = Kh + SD;
    _Float16* Wqh = Vh + SD;
    _Float16* Wkh = Wqh + WD;
    _Float16* Wvh = Wkh + WD;
    _Float16* Woh = Wvh + WD;
    _Float16* qh  = Woh + WD;
    _Float16* kh  = qh + SD;
    _Float16* vh  = kh + SD;
    _Float16* Vt  = Qh;   // alias: Qh dead after projections
    _Float16* at  = Kh;   // alias: Kh dead after projections

    CvtArgs ca;
    ca.src[0] = Q;  ca.dst[0] = Qh;  ca.n[0] = (int)SD;
    ca.src[1] = K;  ca.dst[1] = Kh;  ca.n[1] = (int)SD;
    ca.src[2] = V;  ca.dst[2] = Vh;  ca.n[2] = (int)SD;
    ca.src[3] = Wq; ca.dst[3] = Wqh; ca.n[3] = (int)WD;
    ca.src[4] = Wk; ca.dst[4] = Wkh; ca.n[4] = (int)WD;
    ca.src[5] = Wv; ca.dst[5] = Wvh; ca.n[5] = (int)WD;
    ca.src[6] = Wo; ca.dst[6] = Woh; ca.n[6] = (int)WD;
    cvt_kernel<<<dim3(1024, 1, 7), 256, 0, stream>>>(ca);

    QKVArgs ga;
    ga.A[0] = Qh; ga.W[0] = Wqh; ga.bias[0] = bq; ga.C[0] = qh; ga.scale[0] = 0.125f; // fold 1/sqrt(64)
    ga.A[1] = Kh; ga.W[1] = Wkh; ga.bias[1] = bk; ga.C[1] = kh; ga.scale[1] = 1.0f;
    ga.A[2] = Vh; ga.W[2] = Wvh; ga.bias[2] = bv; ga.C[2] = vh; ga.scale[2] = 1.0f;
    gemm_qkv<<<dim3(8, 32, 3), 256, 0, stream>>>(ga);

    transpose_v<<<dim3(32, 16), 256, 0, stream>>>(vh, Vt);
    attn_kernel<<<dim3(32, 16), 256, 0, stream>>>(qh, kh, Vt, at);
    gemm_out_k<<<dim3(8, 32), 256, 0, stream>>>(at, Woh, bo, (float*)d_out);
}

// Round 3
// 183.166 us; speedup vs baseline: 1.2785x; 1.2785x over previous
//
#include <hip/hip_runtime.h>
#include <hip/hip_bf16.h>
#include <stdint.h>

#define S_LEN  2048
#define DMODEL 1024
#define NHEADS 16
#define HDIM   64

typedef __attribute__((ext_vector_type(8))) _Float16 half8;
typedef __attribute__((ext_vector_type(4))) _Float16 half4;
typedef __attribute__((ext_vector_type(4))) float    f32x4;

// ---------------- fp32 -> fp16 convert ----------------
struct CvtArgs {
    const float* src[7];
    _Float16*    dst[7];
    int          n[7];
};

__global__ __launch_bounds__(256) void cvt_kernel(CvtArgs a) {
    const int z = blockIdx.z;
    const float* __restrict__ src = a.src[z];
    _Float16* __restrict__ dst = a.dst[z];
    const int n = a.n[z];
    const int stride = gridDim.x * blockDim.x * 8;
    for (int i = (blockIdx.x * blockDim.x + threadIdx.x) * 8; i < n; i += stride) {
        float4 v0 = *(const float4*)(src + i);
        float4 v1 = *(const float4*)(src + i + 4);
        half8 o;
        o[0] = (_Float16)v0.x; o[1] = (_Float16)v0.y;
        o[2] = (_Float16)v0.z; o[3] = (_Float16)v0.w;
        o[4] = (_Float16)v1.x; o[5] = (_Float16)v1.y;
        o[6] = (_Float16)v1.z; o[7] = (_Float16)v1.w;
        *(half8*)(dst + i) = o;
    }
}

// ---------------- GEMM: C[M=2048][N=1024] = A[2048][1024] x W[1024][1024]^T + bias ----------------
__device__ __forceinline__ void gload16(const _Float16* g, _Float16* l) {
    __builtin_amdgcn_global_load_lds(
        (__attribute__((address_space(1))) void*)const_cast<_Float16*>(g),
        (__attribute__((address_space(3))) void*)l, 16, 0, 0);
}

template<typename OT>
__device__ __forceinline__ void gemm_body(
    const _Float16* __restrict__ A,
    const _Float16* __restrict__ W,
    const float*    __restrict__ bias,
    OT* __restrict__ C, float scale)
{
    __shared__ _Float16 As[64 * 32];
    __shared__ _Float16 Bs[128 * 32];
    const int tid  = threadIdx.x;
    const int lane = tid & 63, wid = tid >> 6;
    const int row0 = blockIdx.y * 64;
    const int col0 = blockIdx.x * 128;
    const int wr = wid >> 1, wc = wid & 1;
    const int lr = lane & 15, lg = lane >> 4;

    f32x4 acc[2][4];
#pragma unroll
    for (int i = 0; i < 2; i++)
#pragma unroll
        for (int j = 0; j < 4; j++) acc[i][j] = (f32x4)(0.0f);

    for (int k0 = 0; k0 < DMODEL; k0 += 32) {
        {
            const int g = wid * 64 + lane;
            gload16(A + (size_t)(row0 + (g >> 2)) * DMODEL + k0 + (g & 3) * 8,
                    As + (size_t)wid * 64 * 8);
        }
#pragma unroll
        for (int r = 0; r < 2; r++) {
            const int g = r * 256 + wid * 64 + lane;
            gload16(W + (size_t)(col0 + (g >> 2)) * DMODEL + k0 + (g & 3) * 8,
                    Bs + ((size_t)r * 256 + wid * 64) * 8);
        }
        __syncthreads();
        half8 af[2], bfr[4];
#pragma unroll
        for (int i = 0; i < 2; i++)
            af[i] = *(const half8*)(As + (wr * 32 + i * 16 + lr) * 32 + lg * 8);
#pragma unroll
        for (int j = 0; j < 4; j++)
            bfr[j] = *(const half8*)(Bs + (wc * 64 + j * 16 + lr) * 32 + lg * 8);
#pragma unroll
        for (int i = 0; i < 2; i++)
#pragma unroll
            for (int j = 0; j < 4; j++)
                acc[i][j] = __builtin_amdgcn_mfma_f32_16x16x32_f16(af[i], bfr[j], acc[i][j], 0, 0, 0);
        __syncthreads();
    }
#pragma unroll
    for (int i = 0; i < 2; i++)
#pragma unroll
        for (int j = 0; j < 4; j++) {
            const int row = row0 + wr * 32 + i * 16 + lg * 4;
            const int col = col0 + wc * 64 + j * 16 + lr;
            const float b = bias[col];
#pragma unroll
            for (int rj = 0; rj < 4; rj++) {
                float v = (acc[i][j][rj] + b) * scale;
                if constexpr (sizeof(OT) == 2)
                    C[(size_t)(row + rj) * DMODEL + col] = (OT)(_Float16)v;
                else
                    C[(size_t)(row + rj) * DMODEL + col] = v;
            }
        }
}

struct QKVArgs {
    const _Float16* A[3];
    const _Float16* W[3];
    const float*    bias[3];
    _Float16*       C[3];
    float           scale[3];
};

__global__ __launch_bounds__(256) void gemm_qkv(QKVArgs a) {
    const int z = blockIdx.z;
    gemm_body<_Float16>(a.A[z], a.W[z], a.bias[z], a.C[z], a.scale[z]);
}

__global__ __launch_bounds__(256) void gemm_out_k(const _Float16* __restrict__ A,
                                                  const _Float16* __restrict__ W,
                                                  const float* __restrict__ bias,
                                                  float* __restrict__ C) {
    gemm_body<float>(A, W, bias, C, 1.0f);
}

// ---------------- V transpose: v[2048][1024] -> Vt[16][64][2048] ----------------
__global__ __launch_bounds__(256) void transpose_v(const _Float16* __restrict__ v,
                                                   _Float16* __restrict__ Vt) {
    __shared__ _Float16 t[64][72];
    const int s0 = blockIdx.x * 64;
    const int h  = blockIdx.y;
    const int tid = threadIdx.x;
#pragma unroll
    for (int r = 0; r < 2; r++) {
        const int g = r * 256 + tid;
        const int sr = g >> 3, c8 = (g & 7) * 8;
        *(half8*)(&t[sr][c8]) = *(const half8*)(v + (size_t)(s0 + sr) * DMODEL + h * HDIM + c8);
    }
    __syncthreads();
#pragma unroll
    for (int r = 0; r < 2; r++) {
        const int g = r * 256 + tid;
        const int d = g >> 3, c8 = (g & 7) * 8;
        half8 o;
#pragma unroll
        for (int j = 0; j < 8; j++) o[j] = t[c8 + j][d];
        *(half8*)(Vt + (size_t)(h * HDIM + d) * S_LEN + s0 + c8) = o;
    }
}

// ---------------- causal flash attention, swapped-QK^T + split-K ----------------
// grid (64, 16): x -> {qt = 31-(x>>1) [heavy first], split s = x&1}; 4 waves x 16 q-rows.
// Swapped mfma(K,Q): D[key][q], col=q=lane&15 -> softmax row state is LANE-LOCAL
// (2 shfl_xor over the lg dim instead of 8-deep chains). Emits unnormalized fp16
// partials + (m,l) per row; combine_kernel merges the two splits.
__global__ __launch_bounds__(256, 4) void attn_kernel(
    const _Float16* __restrict__ q,
    const _Float16* __restrict__ k,
    const _Float16* __restrict__ Vt,
    _Float16* __restrict__ Opart,   // [2][16][2048][64] fp16, unnormalized
    float2* __restrict__ ml)        // [2][16][2048] (m, l)
{
    __shared__ _Float16 P[4][16][72];   // per-wave P tile [q=16][key=64], stride 144B
    const int tid = threadIdx.x, lane = tid & 63, wid = tid >> 6;
    const int s  = blockIdx.x & 1;
    const int qt = 31 - ((int)blockIdx.x >> 1);
    const int h  = blockIdx.y;
    const int q0 = qt * 64 + wid * 16;
    const int lr = lane & 15, lg = lane >> 4;

    half8 qf[2];
#pragma unroll
    for (int ds = 0; ds < 2; ds++)
        qf[ds] = *(const half8*)(q + (size_t)(q0 + lr) * DMODEL + h * HDIM + ds * 32 + lg * 8);

    float m = -1e30f, lsum = 0.0f;
    f32x4 od[4];
#pragma unroll
    for (int dt = 0; dt < 4; dt++) od[dt] = (f32x4)(0.0f);

    const int T  = qt + 1;
    const int t0 = s ? (T >> 1) : 0;
    const int t1 = s ? T : (T >> 1);
    const int srcb = lg * 20;   // (lane&48) + lg*4 : broadcast source base for od rows

    for (int t = t0; t < t1; t++) {
        const int k0 = t * 64;
        f32x4 sc[4];
#pragma unroll
        for (int kt = 0; kt < 4; kt++) {
            sc[kt] = (f32x4)(0.0f);
#pragma unroll
            for (int ds = 0; ds < 2; ds++) {
                half8 kf = *(const half8*)(k + (size_t)(k0 + kt * 16 + lr) * DMODEL + h * HDIM + ds * 32 + lg * 8);
                sc[kt] = __builtin_amdgcn_mfma_f32_16x16x32_f16(kf, qf[ds], sc[kt], 0, 0, 0);  // SWAPPED
            }
        }
        // sc[kt][r] = S[key = k0+kt*16+lg*4+r][q = q0+lr]
        if (k0 + 63 > q0) {   // diagonal tile(s): causal mask
            const int qrow = q0 + lr;
#pragma unroll
            for (int kt = 0; kt < 4; kt++) {
                const int kb = k0 + kt * 16 + lg * 4;
#pragma unroll
                for (int r = 0; r < 4; r++)
                    if (kb + r > qrow) sc[kt][r] = -1e30f;
            }
        }
        // lane-local online softmax for q-row lr (16 values in regs + 2 shuffles over lg)
        float vmax = sc[0][0];
#pragma unroll
        for (int kt = 0; kt < 4; kt++)
#pragma unroll
            for (int r = 0; r < 4; r++) vmax = fmaxf(vmax, sc[kt][r]);
        vmax = fmaxf(vmax, __shfl_xor(vmax, 16));
        vmax = fmaxf(vmax, __shfl_xor(vmax, 32));
        const float mnew = fmaxf(m, vmax);
        const float sfac = __expf(m - mnew);
        float psum = 0.0f;
#pragma unroll
        for (int kt = 0; kt < 4; kt++)
#pragma unroll
            for (int r = 0; r < 4; r++) {
                const float p = __expf(sc[kt][r] - mnew);
                sc[kt][r] = p;
                psum += p;
            }
        psum += __shfl_xor(psum, 16);
        psum += __shfl_xor(psum, 32);
        lsum = lsum * sfac + psum;
        m = mnew;
        // broadcast sfac to od rows (od row = lg*4+r lives in lane lr'=lg*4+r)
        float sf[4];
#pragma unroll
        for (int r = 0; r < 4; r++) sf[r] = __shfl(sfac, srcb + r);
#pragma unroll
        for (int dt = 0; dt < 4; dt++)
#pragma unroll
            for (int r = 0; r < 4; r++) od[dt][r] *= sf[r];
        // P[q=lr][key]: 4 consecutive keys per half4 store
#pragma unroll
        for (int kt = 0; kt < 4; kt++) {
            half4 ph;
#pragma unroll
            for (int r = 0; r < 4; r++) ph[r] = (_Float16)sc[kt][r];
            *(half4*)(&P[wid][lr][kt * 16 + lg * 4]) = ph;
        }
#pragma unroll
        for (int ks = 0; ks < 2; ks++) {
            half8 pa = *(const half8*)(&P[wid][lr][ks * 32 + lg * 8]);
#pragma unroll
            for (int dt = 0; dt < 4; dt++) {
                half8 vb = *(const half8*)(Vt + (size_t)(h * HDIM + dt * 16 + lr) * S_LEN + k0 + ks * 32 + lg * 8);
                od[dt] = __builtin_amdgcn_mfma_f32_16x16x32_f16(pa, vb, od[dt], 0, 0, 0);
            }
        }
    }
    // store unnormalized partials + (m,l)
    _Float16* Ob = Opart + ((size_t)(s * NHEADS + h) * S_LEN) * HDIM;
#pragma unroll
    for (int dt = 0; dt < 4; dt++)
#pragma unroll
        for (int r = 0; r < 4; r++)
            Ob[(size_t)(q0 + lg * 4 + r) * HDIM + dt * 16 + lr] = (_Float16)od[dt][r];
    if (lane < 16) {
        float2 v; v.x = m; v.y = lsum;
        ml[(size_t)(s * NHEADS + h) * S_LEN + q0 + lr] = v;
    }
}

// ---------------- split-K combine: at[q][h*64+d] fp16 ----------------
__global__ __launch_bounds__(256) void combine_kernel(
    const _Float16* __restrict__ Opart, const float2* __restrict__ ml,
    _Float16* __restrict__ at)
{
    const int idx = blockIdx.x * 256 + threadIdx.x;   // 262144 threads, 8 d each
    const int qrow = idx >> 7;
    const int c8 = (idx & 127) * 8;
    const int h = c8 >> 6, d = c8 & 63;
    const size_t b0 = ((size_t)h * S_LEN + qrow) * HDIM + d;
    const size_t b1 = ((size_t)(NHEADS + h) * S_LEN + qrow) * HDIM + d;
    half8 o0 = *(const half8*)(Opart + b0);
    half8 o1 = *(const half8*)(Opart + b1);
    float2 ml0 = ml[(size_t)h * S_LEN + qrow];
    float2 ml1 = ml[(size_t)(NHEADS + h) * S_LEN + qrow];
    const float M  = fmaxf(ml0.x, ml1.x);
    const float w0 = __expf(ml0.x - M);
    const float w1 = __expf(ml1.x - M);
    const float inv = 1.0f / (ml0.y * w0 + ml1.y * w1);
    const float a0 = w0 * inv, a1 = w1 * inv;
    half8 o;
#pragma unroll
    for (int j = 0; j < 8; j++)
        o[j] = (_Float16)((float)o0[j] * a0 + (float)o1[j] * a1);
    *(half8*)(at + (size_t)qrow * DMODEL + c8) = o;
}

// ---------------- launch ----------------
extern "C" void kernel_launch(void* const* d_in, const int* in_sizes, int n_in,
                              void* d_out, int out_size, void* d_ws, size_t ws_size,
                              hipStream_t stream) {
    const float* Q  = (const float*)d_in[0];
    const float* K  = (const float*)d_in[1];
    const float* V  = (const float*)d_in[2];
    const float* Wq = (const float*)d_in[3];
    const float* bq = (const float*)d_in[4];
    const float* Wk = (const float*)d_in[5];
    const float* bk = (const float*)d_in[6];
    const float* Wv = (const float*)d_in[7];
    const float* bv = (const float*)d_in[8];
    const float* Wo = (const float*)d_in[9];
    const float* bo = (const float*)d_in[10];

    // 32 MB workspace layout (MB offsets), with liveness-based aliasing:
    //  0: Qh(4)        -> Vt(4)      after gemm_qkv
    //  4: Kh(4), 8: Vh(4) -> Opart(8) during attn
    // 12: Wqh(2)       -> ml(0.5)    during attn
    // 14: Wkh(2),16: Wvh(2) -> at(4) after attn
    // 18: Woh(2)  [live to end]
    // 20: qh(4)  24: kh(4)  28: vh(4)
    char* w = (char*)d_ws;
    const size_t MB = 1 << 20;
    _Float16* Qh  = (_Float16*)(w + 0 * MB);
    _Float16* Kh  = (_Float16*)(w + 4 * MB);
    _Float16* Vh  = (_Float16*)(w + 8 * MB);
    _Float16* Wqh = (_Float16*)(w + 12 * MB);
    _Float16* Wkh = (_Float16*)(w + 14 * MB);
    _Float16* Wvh = (_Float16*)(w + 16 * MB);
    _Float16* Woh = (_Float16*)(w + 18 * MB);
    _Float16* qh  = (_Float16*)(w + 20 * MB);
    _Float16* kh  = (_Float16*)(w + 24 * MB);
    _Float16* vh  = (_Float16*)(w + 28 * MB);
    _Float16* Vt    = (_Float16*)(w + 0 * MB);
    _Float16* Opart = (_Float16*)(w + 4 * MB);
    float2*   ml    = (float2*)  (w + 12 * MB);
    _Float16* at    = (_Float16*)(w + 14 * MB);

    const size_t SD = (size_t)S_LEN * DMODEL;
    const size_t WD = (size_t)DMODEL * DMODEL;

    CvtArgs ca;
    ca.src[0] = Q;  ca.dst[0] = Qh;  ca.n[0] = (int)SD;
    ca.src[1] = K;  ca.dst[1] = Kh;  ca.n[1] = (int)SD;
    ca.src[2] = V;  ca.dst[2] = Vh;  ca.n[2] = (int)SD;
    ca.src[3] = Wq; ca.dst[3] = Wqh; ca.n[3] = (int)WD;
    ca.src[4] = Wk; ca.dst[4] = Wkh; ca.n[4] = (int)WD;
    ca.src[5] = Wv; ca.dst[5] = Wvh; ca.n[5] = (int)WD;
    ca.src[6] = Wo; ca.dst[6] = Woh; ca.n[6] = (int)WD;
    cvt_kernel<<<dim3(1024, 1, 7), 256, 0, stream>>>(ca);

    QKVArgs ga;
    ga.A[0] = Qh; ga.W[0] = Wqh; ga.bias[0] = bq; ga.C[0] = qh; ga.scale[0] = 0.125f;
    ga.A[1] = Kh; ga.W[1] = Wkh; ga.bias[1] = bk; ga.C[1] = kh; ga.scale[1] = 1.0f;
    ga.A[2] = Vh; ga.W[2] = Wvh; ga.bias[2] = bv; ga.C[2] = vh; ga.scale[2] = 1.0f;
    gemm_qkv<<<dim3(8, 32, 3), 256, 0, stream>>>(ga);

    transpose_v<<<dim3(32, 16), 256, 0, stream>>>(vh, Vt);
    attn_kernel<<<dim3(64, 16), 256, 0, stream>>>(qh, kh, Vt, Opart, ml);
    combine_kernel<<<dim3(1024), 256, 0, stream>>>(Opart, ml, at);
    gemm_out_k<<<dim3(8, 32), 256, 0, stream>>>(at, Woh, bo, (float*)d_out);
}

// Round 4
// 154.047 us; speedup vs baseline: 1.5202x; 1.1890x over previous
//
#include <hip/hip_runtime.h>
#include <hip/hip_bf16.h>
#include <stdint.h>

#define S_LEN  2048
#define DMODEL 1024
#define NHEADS 16
#define HDIM   64
#define CHUNK  6      // k-tiles (of 64 keys) per attention block
#define NCHUNK 102    // sum over qt of ceil((qt+1)/CHUNK)

typedef __attribute__((ext_vector_type(8))) _Float16 half8;
typedef __attribute__((ext_vector_type(4))) _Float16 half4;
typedef __attribute__((ext_vector_type(4))) float    f32x4;

struct AttnMap { int base[33]; };   // base[qt] = # chunks before q-tile qt; base[32]=NCHUNK

// ---------------- fp32 -> fp16 convert ----------------
struct CvtArgs {
    const float* src[7];
    _Float16*    dst[7];
    int          n[7];
};

__global__ __launch_bounds__(256) void cvt_kernel(CvtArgs a) {
    const int z = blockIdx.z;
    const float* __restrict__ src = a.src[z];
    _Float16* __restrict__ dst = a.dst[z];
    const int n = a.n[z];
    const int stride = gridDim.x * blockDim.x * 8;
    for (int i = (blockIdx.x * blockDim.x + threadIdx.x) * 8; i < n; i += stride) {
        float4 v0 = *(const float4*)(src + i);
        float4 v1 = *(const float4*)(src + i + 4);
        half8 o;
        o[0] = (_Float16)v0.x; o[1] = (_Float16)v0.y;
        o[2] = (_Float16)v0.z; o[3] = (_Float16)v0.w;
        o[4] = (_Float16)v1.x; o[5] = (_Float16)v1.y;
        o[6] = (_Float16)v1.z; o[7] = (_Float16)v1.w;
        *(half8*)(dst + i) = o;
    }
}

// ---------------- GEMM (m97 128x128 tile): C = A x W^T + bias ----------------
__device__ __forceinline__ void gload16(const _Float16* g, _Float16* l) {
    __builtin_amdgcn_global_load_lds(
        (__attribute__((address_space(1))) void*)const_cast<_Float16*>(g),
        (__attribute__((address_space(3))) void*)l, 16, 0, 0);
}

template<typename OT>
__device__ __forceinline__ void gemm_body(
    const _Float16* __restrict__ A,
    const _Float16* __restrict__ W,
    const float*    __restrict__ bias,
    OT* __restrict__ C, float scale)
{
    __shared__ _Float16 As[128 * 32];   // linear [row][k]
    __shared__ _Float16 Bs[128 * 32];   // linear [col][k]
    const int tid  = threadIdx.x;
    const int lane = tid & 63, wid = tid >> 6;
    const int row0 = blockIdx.y * 128;
    const int col0 = blockIdx.x * 128;
    const int wr = wid >> 1, wc = wid & 1;
    const int lr = lane & 15, lg = lane >> 4;

    f32x4 acc[4][4];
#pragma unroll
    for (int i = 0; i < 4; i++)
#pragma unroll
        for (int j = 0; j < 4; j++) acc[i][j] = (f32x4)(0.0f);

    for (int k0 = 0; k0 < DMODEL; k0 += 32) {
#pragma unroll
        for (int r = 0; r < 2; r++) {   // A: 512 granules of 16B
            const int g = r * 256 + wid * 64 + lane;
            gload16(A + (size_t)(row0 + (g >> 2)) * DMODEL + k0 + (g & 3) * 8,
                    As + ((size_t)r * 256 + wid * 64) * 8);
        }
#pragma unroll
        for (int r = 0; r < 2; r++) {   // B: 512 granules
            const int g = r * 256 + wid * 64 + lane;
            gload16(W + (size_t)(col0 + (g >> 2)) * DMODEL + k0 + (g & 3) * 8,
                    Bs + ((size_t)r * 256 + wid * 64) * 8);
        }
        __syncthreads();
        half8 af[4], bfr[4];
#pragma unroll
        for (int i = 0; i < 4; i++)
            af[i] = *(const half8*)(As + (wr * 64 + i * 16 + lr) * 32 + lg * 8);
#pragma unroll
        for (int j = 0; j < 4; j++)
            bfr[j] = *(const half8*)(Bs + (wc * 64 + j * 16 + lr) * 32 + lg * 8);
#pragma unroll
        for (int i = 0; i < 4; i++)
#pragma unroll
            for (int j = 0; j < 4; j++)
                acc[i][j] = __builtin_amdgcn_mfma_f32_16x16x32_f16(af[i], bfr[j], acc[i][j], 0, 0, 0);
        __syncthreads();
    }
#pragma unroll
    for (int i = 0; i < 4; i++)
#pragma unroll
        for (int j = 0; j < 4; j++) {
            const int row = row0 + wr * 64 + i * 16 + lg * 4;
            const int col = col0 + wc * 64 + j * 16 + lr;
            const float b = bias[col];
#pragma unroll
            for (int rj = 0; rj < 4; rj++) {
                float v = (acc[i][j][rj] + b) * scale;
                if constexpr (sizeof(OT) == 2)
                    C[(size_t)(row + rj) * DMODEL + col] = (OT)(_Float16)v;
                else
                    C[(size_t)(row + rj) * DMODEL + col] = v;
            }
        }
}

struct QKVArgs {
    const _Float16* A[3];
    const _Float16* W[3];
    const float*    bias[3];
    _Float16*       C[3];
    float           scale[3];
};

__global__ __launch_bounds__(256) void gemm_qkv(QKVArgs a) {
    const int z = blockIdx.z;
    gemm_body<_Float16>(a.A[z], a.W[z], a.bias[z], a.C[z], a.scale[z]);
}

__global__ __launch_bounds__(256) void gemm_out_k(const _Float16* __restrict__ A,
                                                  const _Float16* __restrict__ W,
                                                  const float* __restrict__ bias,
                                                  float* __restrict__ C) {
    gemm_body<float>(A, W, bias, C, 1.0f);
}

// ---------------- V transpose: v[2048][1024] -> Vt[16][64][2048] ----------------
__global__ __launch_bounds__(256) void transpose_v(const _Float16* __restrict__ v,
                                                   _Float16* __restrict__ Vt) {
    __shared__ _Float16 t[64][72];
    const int s0 = blockIdx.x * 64;
    const int h  = blockIdx.y;
    const int tid = threadIdx.x;
#pragma unroll
    for (int r = 0; r < 2; r++) {
        const int g = r * 256 + tid;
        const int sr = g >> 3, c8 = (g & 7) * 8;
        *(half8*)(&t[sr][c8]) = *(const half8*)(v + (size_t)(s0 + sr) * DMODEL + h * HDIM + c8);
    }
    __syncthreads();
#pragma unroll
    for (int r = 0; r < 2; r++) {
        const int g = r * 256 + tid;
        const int d = g >> 3, c8 = (g & 7) * 8;
        half8 o;
#pragma unroll
        for (int j = 0; j < 8; j++) o[j] = t[c8 + j][d];
        *(half8*)(Vt + (size_t)(h * HDIM + d) * S_LEN + s0 + c8) = o;
    }
}

// ---------------- causal flash attention, balanced chunked split-K ----------------
// grid (NCHUNK, 16). Block -> (qt, chunk c) via prefix map; processes k-tiles
// [c*CHUNK, min(qt+1,(c+1)*CHUNK)). 4 waves x 16 q-rows. Swapped mfma(K,Q):
// softmax state lane-local. Defer-max (THR=8) skips O-rescale on most steps.
// Emits NORMALIZED fp16 partials + (m,l); combine merges <=6 chunks per row.
__global__ __launch_bounds__(256, 4) void attn_kernel(
    const _Float16* __restrict__ q,
    const _Float16* __restrict__ k,
    const _Float16* __restrict__ Vt,
    _Float16* __restrict__ Opart,   // [16][NCHUNK][64 rows][64 d], normalized
    float2* __restrict__ ml,        // [16][NCHUNK][64 rows]
    AttnMap map)
{
    __shared__ _Float16 P[4][16][72];
    const int tid = threadIdx.x, lane = tid & 63, wid = tid >> 6;
    const int x = blockIdx.x, h = blockIdx.y;
    int qt = 0;
    while (map.base[qt + 1] <= x) qt++;       // uniform scalar scan, <=32 iters
    const int c  = x - map.base[qt];
    const int q0 = qt * 64 + wid * 16;
    const int lr = lane & 15, lg = lane >> 4;
    const int srcb = lg * 20;                 // lane holding state for od row lg*4+r

    half8 qf[2];
#pragma unroll
    for (int ds = 0; ds < 2; ds++)
        qf[ds] = *(const half8*)(q + (size_t)(q0 + lr) * DMODEL + h * HDIM + ds * 32 + lg * 8);

    float m = -1e30f, lsum = 0.0f;
    f32x4 od[4];
#pragma unroll
    for (int dt = 0; dt < 4; dt++) od[dt] = (f32x4)(0.0f);

    const int T  = qt + 1;
    const int t0 = c * CHUNK;
    const int t1 = (T < t0 + CHUNK) ? T : (t0 + CHUNK);

    for (int t = t0; t < t1; t++) {
        const int k0 = t * 64;
        f32x4 sc[4];
#pragma unroll
        for (int kt = 0; kt < 4; kt++) {
            sc[kt] = (f32x4)(0.0f);
#pragma unroll
            for (int ds = 0; ds < 2; ds++) {
                half8 kf = *(const half8*)(k + (size_t)(k0 + kt * 16 + lr) * DMODEL + h * HDIM + ds * 32 + lg * 8);
                sc[kt] = __builtin_amdgcn_mfma_f32_16x16x32_f16(kf, qf[ds], sc[kt], 0, 0, 0);  // swapped
            }
        }
        // sc[kt][r] = S[key=k0+kt*16+lg*4+r][q=q0+lr]
        if (k0 + 63 > q0) {   // diagonal tile(s): causal mask (min-row trigger)
            const int qrow = q0 + lr;
#pragma unroll
            for (int kt = 0; kt < 4; kt++) {
                const int kb = k0 + kt * 16 + lg * 4;
#pragma unroll
                for (int r = 0; r < 4; r++)
                    if (kb + r > qrow) sc[kt][r] = -1e30f;
            }
        }
        float vmax = sc[0][0];
#pragma unroll
        for (int kt = 0; kt < 4; kt++)
#pragma unroll
            for (int r = 0; r < 4; r++) vmax = fmaxf(vmax, sc[kt][r]);
        vmax = fmaxf(vmax, __shfl_xor(vmax, 16));
        vmax = fmaxf(vmax, __shfl_xor(vmax, 32));
        // T13 defer-max: only rescale when max grew by > 8
        if (!__all(vmax <= m + 8.0f)) {
            const float mnew = fmaxf(m, vmax);
            const float sfac = __expf(m - mnew);
            m = mnew;
            lsum *= sfac;
            float sf[4];
#pragma unroll
            for (int r = 0; r < 4; r++) sf[r] = __shfl(sfac, srcb + r);
#pragma unroll
            for (int dt = 0; dt < 4; dt++)
#pragma unroll
                for (int r = 0; r < 4; r++) od[dt][r] *= sf[r];
        }
        float psum = 0.0f;
#pragma unroll
        for (int kt = 0; kt < 4; kt++)
#pragma unroll
            for (int r = 0; r < 4; r++) {
                const float p = __expf(sc[kt][r] - m);   // bounded by e^8
                sc[kt][r] = p;
                psum += p;
            }
        psum += __shfl_xor(psum, 16);
        psum += __shfl_xor(psum, 32);
        lsum += psum;
#pragma unroll
        for (int kt = 0; kt < 4; kt++) {
            half4 ph;
#pragma unroll
            for (int r = 0; r < 4; r++) ph[r] = (_Float16)sc[kt][r];
            *(half4*)(&P[wid][lr][kt * 16 + lg * 4]) = ph;
        }
#pragma unroll
        for (int ks = 0; ks < 2; ks++) {
            half8 pa = *(const half8*)(&P[wid][lr][ks * 32 + lg * 8]);
#pragma unroll
            for (int dt = 0; dt < 4; dt++) {
                half8 vb = *(const half8*)(Vt + (size_t)(h * HDIM + dt * 16 + lr) * S_LEN + k0 + ks * 32 + lg * 8);
                od[dt] = __builtin_amdgcn_mfma_f32_16x16x32_f16(pa, vb, od[dt], 0, 0, 0);
            }
        }
    }
    // normalized store (fp16-safe even with defer-max)
    const float inv = 1.0f / lsum;          // state for q-row lr
    float invb[4];
#pragma unroll
    for (int r = 0; r < 4; r++) invb[r] = __shfl(inv, srcb + r);
    _Float16* Ob = Opart + ((size_t)h * NCHUNK + x) * 64 * 64;
#pragma unroll
    for (int dt = 0; dt < 4; dt++)
#pragma unroll
        for (int r = 0; r < 4; r++)
            Ob[(size_t)(wid * 16 + lg * 4 + r) * 64 + dt * 16 + lr] = (_Float16)(od[dt][r] * invb[r]);
    if (lane < 16) {
        float2 v; v.x = m; v.y = lsum;
        ml[((size_t)h * NCHUNK + x) * 64 + wid * 16 + lr] = v;
    }
}

// ---------------- chunk combine: at[q][h*64+d] fp16 ----------------
__global__ __launch_bounds__(256) void combine_kernel(
    const _Float16* __restrict__ Opart, const float2* __restrict__ ml,
    _Float16* __restrict__ at, AttnMap map)
{
    const int idx = blockIdx.x * 256 + threadIdx.x;   // 262144 threads
    const int qrow = idx >> 7;
    const int c8 = (idx & 127) * 8;
    const int h = c8 >> 6, d = c8 & 63;
    const int qt = qrow >> 6;
    const int cb = map.base[qt];
    const int nc = map.base[qt + 1] - cb;
    const int lrow = qrow & 63;

    float M = -1e30f, denom = 0.0f;
    float acc[8];
#pragma unroll
    for (int j = 0; j < 8; j++) acc[j] = 0.0f;
    for (int cc = 0; cc < nc; cc++) {
        const size_t ci = (size_t)h * NCHUNK + cb + cc;
        const float2 mlv = ml[ci * 64 + lrow];
        half8 ov = *(const half8*)(Opart + (ci * 64 + lrow) * 64 + d);
        if (mlv.x > M) {
            const float r = __expf(M - mlv.x);
            denom = denom * r + mlv.y;
#pragma unroll
            for (int j = 0; j < 8; j++) acc[j] = acc[j] * r + (float)ov[j] * mlv.y;
            M = mlv.x;
        } else {
            const float w = __expf(mlv.x - M) * mlv.y;
            denom += w;
#pragma unroll
            for (int j = 0; j < 8; j++) acc[j] += (float)ov[j] * w;
        }
    }
    const float inv = 1.0f / denom;
    half8 o;
#pragma unroll
    for (int j = 0; j < 8; j++) o[j] = (_Float16)(acc[j] * inv);
    *(half8*)(at + (size_t)qrow * DMODEL + c8) = o;
}

// ---------------- launch ----------------
extern "C" void kernel_launch(void* const* d_in, const int* in_sizes, int n_in,
                              void* d_out, int out_size, void* d_ws, size_t ws_size,
                              hipStream_t stream) {
    const float* Q  = (const float*)d_in[0];
    const float* K  = (const float*)d_in[1];
    const float* V  = (const float*)d_in[2];
    const float* Wq = (const float*)d_in[3];
    const float* bq = (const float*)d_in[4];
    const float* Wk = (const float*)d_in[5];
    const float* bk = (const float*)d_in[6];
    const float* Wv = (const float*)d_in[7];
    const float* bv = (const float*)d_in[8];
    const float* Wo = (const float*)d_in[9];
    const float* bo = (const float*)d_in[10];

    // 32 MB workspace, liveness-aliased (MB offsets):
    //  0: Qh(4)  -> Vt(4) after gemm_qkv
    //  4: Kh(4), 8: Vh(4), 12: Wqh(2), 14: Wkh(2), 16: Wvh(2) -> Opart(13.4) @4 during attn
    // 18: Woh(2) [live to end]
    // 20: qh(4) -> at(4) after attn
    // 24: kh(4)
    // 28: vh(4) -> ml(0.84) after transpose
    char* w = (char*)d_ws;
    const size_t MB = 1 << 20;
    _Float16* Qh  = (_Float16*)(w + 0 * MB);
    _Float16* Kh  = (_Float16*)(w + 4 * MB);
    _Float16* Vh  = (_Float16*)(w + 8 * MB);
    _Float16* Wqh = (_Float16*)(w + 12 * MB);
    _Float16* Wkh = (_Float16*)(w + 14 * MB);
    _Float16* Wvh = (_Float16*)(w + 16 * MB);
    _Float16* Woh = (_Float16*)(w + 18 * MB);
    _Float16* qh  = (_Float16*)(w + 20 * MB);
    _Float16* kh  = (_Float16*)(w + 24 * MB);
    _Float16* vh  = (_Float16*)(w + 28 * MB);
    _Float16* Vt    = (_Float16*)(w + 0 * MB);
    _Float16* Opart = (_Float16*)(w + 4 * MB);   // 13.37 MB < 14
    float2*   ml    = (float2*)  (w + 28 * MB);  // 0.84 MB
    _Float16* at    = (_Float16*)(w + 20 * MB);

    const size_t SD = (size_t)S_LEN * DMODEL;
    const size_t WD = (size_t)DMODEL * DMODEL;

    CvtArgs ca;
    ca.src[0] = Q;  ca.dst[0] = Qh;  ca.n[0] = (int)SD;
    ca.src[1] = K;  ca.dst[1] = Kh;  ca.n[1] = (int)SD;
    ca.src[2] = V;  ca.dst[2] = Vh;  ca.n[2] = (int)SD;
    ca.src[3] = Wq; ca.dst[3] = Wqh; ca.n[3] = (int)WD;
    ca.src[4] = Wk; ca.dst[4] = Wkh; ca.n[4] = (int)WD;
    ca.src[5] = Wv; ca.dst[5] = Wvh; ca.n[5] = (int)WD;
    ca.src[6] = Wo; ca.dst[6] = Woh; ca.n[6] = (int)WD;
    cvt_kernel<<<dim3(1024, 1, 7), 256, 0, stream>>>(ca);

    QKVArgs ga;
    ga.A[0] = Qh; ga.W[0] = Wqh; ga.bias[0] = bq; ga.C[0] = qh; ga.scale[0] = 0.125f;
    ga.A[1] = Kh; ga.W[1] = Wkh; ga.bias[1] = bk; ga.C[1] = kh; ga.scale[1] = 1.0f;
    ga.A[2] = Vh; ga.W[2] = Wvh; ga.bias[2] = bv; ga.C[2] = vh; ga.scale[2] = 1.0f;
    gemm_qkv<<<dim3(8, 16, 3), 256, 0, stream>>>(ga);

    transpose_v<<<dim3(32, 16), 256, 0, stream>>>(vh, Vt);

    AttnMap map;
    map.base[0] = 0;
    for (int qt = 0; qt < 32; qt++)
        map.base[qt + 1] = map.base[qt] + (qt + 1 + CHUNK - 1) / CHUNK;
    // map.base[32] == NCHUNK (102)

    attn_kernel<<<dim3(NCHUNK, NHEADS), 256, 0, stream>>>(qh, kh, Vt, Opart, ml, map);
    combine_kernel<<<dim3(1024), 256, 0, stream>>>(Opart, ml, at, map);
    gemm_out_k<<<dim3(8, 16), 256, 0, stream>>>(at, Woh, bo, (float*)d_out);
}

// Round 5
// 110.614 us; speedup vs baseline: 2.1170x; 1.3926x over previous
//
#include <hip/hip_runtime.h>
#include <hip/hip_bf16.h>
#include <stdint.h>

#define S_LEN  2048
#define DMODEL 1024
#define NHEADS 16
#define HDIM   64
#define CHUNK  5      // k-tiles (64 keys) per attention chunk-block
#define NCHUNK 61     // sum over 16 q-tiles of ceil(2*(qt+1)/CHUNK)

typedef __attribute__((ext_vector_type(8))) _Float16 half8;
typedef __attribute__((ext_vector_type(4))) _Float16 half4;
typedef __attribute__((ext_vector_type(4))) float    f32x4;

struct AttnMap { int base[17]; };   // base[qt] = chunks before q-tile qt (128-row tiles)

// ---------------- fp32 -> fp16 convert ----------------
struct CvtArgs {
    const float* src[7];
    _Float16*    dst[7];
    int          n[7];
};

__global__ __launch_bounds__(256) void cvt_kernel(CvtArgs a) {
    const int z = blockIdx.z;
    const float* __restrict__ src = a.src[z];
    _Float16* __restrict__ dst = a.dst[z];
    const int n = a.n[z];
    const int stride = gridDim.x * blockDim.x * 8;
    for (int i = (blockIdx.x * blockDim.x + threadIdx.x) * 8; i < n; i += stride) {
        float4 v0 = *(const float4*)(src + i);
        float4 v1 = *(const float4*)(src + i + 4);
        half8 o;
        o[0] = (_Float16)v0.x; o[1] = (_Float16)v0.y;
        o[2] = (_Float16)v0.z; o[3] = (_Float16)v0.w;
        o[4] = (_Float16)v1.x; o[5] = (_Float16)v1.y;
        o[6] = (_Float16)v1.z; o[7] = (_Float16)v1.w;
        *(half8*)(dst + i) = o;
    }
}

// ---------------- GEMM (m97 128x128 tile): C = A x W^T + bias ----------------
__device__ __forceinline__ void gload16(const _Float16* g, _Float16* l) {
    __builtin_amdgcn_global_load_lds(
        (__attribute__((address_space(1))) void*)const_cast<_Float16*>(g),
        (__attribute__((address_space(3))) void*)l, 16, 0, 0);
}

template<typename OT>
__device__ __forceinline__ void gemm_body(
    const _Float16* __restrict__ A,
    const _Float16* __restrict__ W,
    const float*    __restrict__ bias,
    OT* __restrict__ C, float scale)
{
    __shared__ _Float16 As[128 * 32];
    __shared__ _Float16 Bs[128 * 32];
    const int tid  = threadIdx.x;
    const int lane = tid & 63, wid = tid >> 6;
    const int row0 = blockIdx.y * 128;
    const int col0 = blockIdx.x * 128;
    const int wr = wid >> 1, wc = wid & 1;
    const int lr = lane & 15, lg = lane >> 4;

    f32x4 acc[4][4];
#pragma unroll
    for (int i = 0; i < 4; i++)
#pragma unroll
        for (int j = 0; j < 4; j++) acc[i][j] = (f32x4)(0.0f);

    for (int k0 = 0; k0 < DMODEL; k0 += 32) {
#pragma unroll
        for (int r = 0; r < 2; r++) {
            const int g = r * 256 + wid * 64 + lane;
            gload16(A + (size_t)(row0 + (g >> 2)) * DMODEL + k0 + (g & 3) * 8,
                    As + ((size_t)r * 256 + wid * 64) * 8);
        }
#pragma unroll
        for (int r = 0; r < 2; r++) {
            const int g = r * 256 + wid * 64 + lane;
            gload16(W + (size_t)(col0 + (g >> 2)) * DMODEL + k0 + (g & 3) * 8,
                    Bs + ((size_t)r * 256 + wid * 64) * 8);
        }
        __syncthreads();
        half8 af[4], bfr[4];
#pragma unroll
        for (int i = 0; i < 4; i++)
            af[i] = *(const half8*)(As + (wr * 64 + i * 16 + lr) * 32 + lg * 8);
#pragma unroll
        for (int j = 0; j < 4; j++)
            bfr[j] = *(const half8*)(Bs + (wc * 64 + j * 16 + lr) * 32 + lg * 8);
        __builtin_amdgcn_s_setprio(1);
#pragma unroll
        for (int i = 0; i < 4; i++)
#pragma unroll
            for (int j = 0; j < 4; j++)
                acc[i][j] = __builtin_amdgcn_mfma_f32_16x16x32_f16(af[i], bfr[j], acc[i][j], 0, 0, 0);
        __builtin_amdgcn_s_setprio(0);
        __syncthreads();
    }
#pragma unroll
    for (int i = 0; i < 4; i++)
#pragma unroll
        for (int j = 0; j < 4; j++) {
            const int row = row0 + wr * 64 + i * 16 + lg * 4;
            const int col = col0 + wc * 64 + j * 16 + lr;
            const float b = bias[col];
#pragma unroll
            for (int rj = 0; rj < 4; rj++) {
                float v = (acc[i][j][rj] + b) * scale;
                if constexpr (sizeof(OT) == 2)
                    C[(size_t)(row + rj) * DMODEL + col] = (OT)(_Float16)v;
                else
                    C[(size_t)(row + rj) * DMODEL + col] = v;
            }
        }
}

struct QKVArgs {
    const _Float16* A[3];
    const _Float16* W[3];
    const float*    bias[3];
    _Float16*       C[3];
    float           scale[3];
};

__global__ __launch_bounds__(256) void gemm_qkv(QKVArgs a) {
    const int z = blockIdx.z;
    gemm_body<_Float16>(a.A[z], a.W[z], a.bias[z], a.C[z], a.scale[z]);
}

__global__ __launch_bounds__(256) void gemm_out_k(const _Float16* __restrict__ A,
                                                  const _Float16* __restrict__ W,
                                                  const float* __restrict__ bias,
                                                  float* __restrict__ C) {
    gemm_body<float>(A, W, bias, C, 1.0f);
}

// ---------------- V transpose: v[2048][1024] -> Vt[16][64][2048] ----------------
__global__ __launch_bounds__(256) void transpose_v(const _Float16* __restrict__ v,
                                                   _Float16* __restrict__ Vt) {
    __shared__ _Float16 t[64][72];
    const int s0 = blockIdx.x * 64;
    const int h  = blockIdx.y;
    const int tid = threadIdx.x;
#pragma unroll
    for (int r = 0; r < 2; r++) {
        const int g = r * 256 + tid;
        const int sr = g >> 3, c8 = (g & 7) * 8;
        *(half8*)(&t[sr][c8]) = *(const half8*)(v + (size_t)(s0 + sr) * DMODEL + h * HDIM + c8);
    }
    __syncthreads();
#pragma unroll
    for (int r = 0; r < 2; r++) {
        const int g = r * 256 + tid;
        const int d = g >> 3, c8 = (g & 7) * 8;
        half8 o;
#pragma unroll
        for (int j = 0; j < 8; j++) o[j] = t[c8 + j][d];
        *(half8*)(Vt + (size_t)(h * HDIM + d) * S_LEN + s0 + c8) = o;
    }
}

// ---------------- causal flash attention ----------------
// grid (NCHUNK, 16), 512 threads = 8 waves x 16 q-rows (q-tile = 128 rows).
// K/V tiles staged in LDS (double-buffered, global_load_lds w/ pre-swizzled
// source; XOR slot^(lr&7) kills the 128B-stride bank conflict). Swapped
// mfma(K,Q): softmax lane-local. Defer-max THR=8. Normalized fp16 partials.
__global__ __launch_bounds__(512, 6) void attn_kernel(
    const _Float16* __restrict__ q,
    const _Float16* __restrict__ k,
    const _Float16* __restrict__ Vt,
    _Float16* __restrict__ Opart,   // [16][NCHUNK][128][64], normalized
    float2* __restrict__ ml,        // [16][NCHUNK][128]
    AttnMap map)
{
    __shared__ _Float16 Kl[2][64 * 64];   // [key row][d slot*8], slot swizzled
    __shared__ _Float16 Vl[2][64 * 64];   // [d row][k slot*8], slot swizzled
    __shared__ _Float16 P[8][16][72];     // per-wave P bounce
    const int tid = threadIdx.x, lane = tid & 63, wid = tid >> 6;
    const int x = blockIdx.x, h = blockIdx.y;
    int qt = 0;
    while (map.base[qt + 1] <= x) qt++;
    const int c  = x - map.base[qt];
    const int q0 = qt * 128 + wid * 16;
    const int lr = lane & 15, lg = lane >> 4;
    const int srcb = lg * 20;             // lane holding softmax state for od row lg*4+r

    const int r8 = lane >> 3, sl = lane & 7;
    const int ssw = (sl ^ (r8 & 7)) * 8;  // pre-swizzled source column (elements)

    half8 qf[2];
#pragma unroll
    for (int ds = 0; ds < 2; ds++)
        qf[ds] = *(const half8*)(q + (size_t)(q0 + lr) * DMODEL + h * HDIM + ds * 32 + lg * 8);

    float m = -1e30f, lsum = 0.0f;
    f32x4 od[4];
#pragma unroll
    for (int dt = 0; dt < 4; dt++) od[dt] = (f32x4)(0.0f);

    const int T2 = 2 * (qt + 1);              // k-tiles for this q-tile
    const int t0 = c * CHUNK;
    const int t1 = (T2 < t0 + CHUNK) ? T2 : (t0 + CHUNK);

    // stage k-tile t into buffer b: each wave issues 1 K + 1 V gload (8 rows each)
    auto stage = [&](int b, int t) {
        const int kb = t * 64;
        gload16(k + (size_t)(kb + wid * 8 + r8) * DMODEL + h * HDIM + ssw,
                &Kl[b][wid * 8 * 64]);
        gload16(Vt + (size_t)(h * HDIM + wid * 8 + r8) * S_LEN + kb + ssw,
                &Vl[b][wid * 8 * 64]);
    };

    int cur = 0;
    stage(0, t0);
    __syncthreads();   // compiler drains vmcnt before barrier -> tile t0 ready

    for (int t = t0; t < t1; t++) {
        if (t + 1 < t1) stage(cur ^ 1, t + 1);
        const int k0 = t * 64;
        f32x4 sc[4];
#pragma unroll
        for (int kt = 0; kt < 4; kt++) sc[kt] = (f32x4)(0.0f);
        __builtin_amdgcn_s_setprio(1);
#pragma unroll
        for (int kt = 0; kt < 4; kt++)
#pragma unroll
            for (int ds = 0; ds < 2; ds++) {
                half8 kf = *(const half8*)(&Kl[cur][(kt * 16 + lr) * 64 + (((ds * 4 + lg) ^ (lr & 7)) * 8)]);
                sc[kt] = __builtin_amdgcn_mfma_f32_16x16x32_f16(kf, qf[ds], sc[kt], 0, 0, 0);  // swapped
            }
        __builtin_amdgcn_s_setprio(0);
        // sc[kt][r] = S[key=k0+kt*16+lg*4+r][q=q0+lr]
        if (k0 + 63 > q0) {
            const int qrow = q0 + lr;
#pragma unroll
            for (int kt = 0; kt < 4; kt++) {
                const int kb2 = k0 + kt * 16 + lg * 4;
#pragma unroll
                for (int r = 0; r < 4; r++)
                    if (kb2 + r > qrow) sc[kt][r] = -1e30f;
            }
        }
        float vmax = sc[0][0];
#pragma unroll
        for (int kt = 0; kt < 4; kt++)
#pragma unroll
            for (int r = 0; r < 4; r++) vmax = fmaxf(vmax, sc[kt][r]);
        vmax = fmaxf(vmax, __shfl_xor(vmax, 16));
        vmax = fmaxf(vmax, __shfl_xor(vmax, 32));
        if (!__all(vmax <= m + 8.0f)) {       // T13 defer-max
            const float mnew = fmaxf(m, vmax);
            const float sfac = __expf(m - mnew);
            m = mnew;
            lsum *= sfac;
            float sf[4];
#pragma unroll
            for (int r = 0; r < 4; r++) sf[r] = __shfl(sfac, srcb + r);
#pragma unroll
            for (int dt = 0; dt < 4; dt++)
#pragma unroll
                for (int r = 0; r < 4; r++) od[dt][r] *= sf[r];
        }
        float psum = 0.0f;
#pragma unroll
        for (int kt = 0; kt < 4; kt++)
#pragma unroll
            for (int r = 0; r < 4; r++) {
                const float p = __expf(sc[kt][r] - m);
                sc[kt][r] = p;
                psum += p;
            }
        psum += __shfl_xor(psum, 16);
        psum += __shfl_xor(psum, 32);
        lsum += psum;
#pragma unroll
        for (int kt = 0; kt < 4; kt++) {
            half4 ph;
#pragma unroll
            for (int r = 0; r < 4; r++) ph[r] = (_Float16)sc[kt][r];
            *(half4*)(&P[wid][lr][kt * 16 + lg * 4]) = ph;
        }
        __builtin_amdgcn_s_setprio(1);
#pragma unroll
        for (int ks = 0; ks < 2; ks++) {
            half8 pa = *(const half8*)(&P[wid][lr][ks * 32 + lg * 8]);
#pragma unroll
            for (int dt = 0; dt < 4; dt++) {
                half8 vb = *(const half8*)(&Vl[cur][(dt * 16 + lr) * 64 + (((ks * 4 + lg) ^ (lr & 7)) * 8)]);
                od[dt] = __builtin_amdgcn_mfma_f32_16x16x32_f16(pa, vb, od[dt], 0, 0, 0);
            }
        }
        __builtin_amdgcn_s_setprio(0);
        __syncthreads();   // stage(cur^1) landed; all waves done reading cur
        cur ^= 1;
    }

    const float inv = 1.0f / lsum;
    float invb[4];
#pragma unroll
    for (int r = 0; r < 4; r++) invb[r] = __shfl(inv, srcb + r);
    _Float16* Ob = Opart + ((size_t)h * NCHUNK + x) * 128 * 64;
#pragma unroll
    for (int dt = 0; dt < 4; dt++)
#pragma unroll
        for (int r = 0; r < 4; r++)
            Ob[(size_t)(wid * 16 + lg * 4 + r) * 64 + dt * 16 + lr] = (_Float16)(od[dt][r] * invb[r]);
    if (lane < 16) {
        float2 v; v.x = m; v.y = lsum;
        ml[((size_t)h * NCHUNK + x) * 128 + wid * 16 + lr] = v;
    }
}

// ---------------- chunk combine: at[q][h*64+d] fp16 ----------------
__global__ __launch_bounds__(256) void combine_kernel(
    const _Float16* __restrict__ Opart, const float2* __restrict__ ml,
    _Float16* __restrict__ at, AttnMap map)
{
    const int idx = blockIdx.x * 256 + threadIdx.x;
    const int qrow = idx >> 7;
    const int c8 = (idx & 127) * 8;
    const int h = c8 >> 6, d = c8 & 63;
    const int qt = qrow >> 7;
    const int cb = map.base[qt];
    const int nc = map.base[qt + 1] - cb;
    const int lrow = qrow & 127;

    float M = -1e30f, denom = 0.0f;
    float acc[8];
#pragma unroll
    for (int j = 0; j < 8; j++) acc[j] = 0.0f;
    for (int cc = 0; cc < nc; cc++) {
        const size_t ci = (size_t)h * NCHUNK + cb + cc;
        const float2 mlv = ml[ci * 128 + lrow];
        half8 ov = *(const half8*)(Opart + (ci * 128 + lrow) * 64 + d);
        if (mlv.x > M) {
            const float r = __expf(M - mlv.x);
            denom = denom * r + mlv.y;
#pragma unroll
            for (int j = 0; j < 8; j++) acc[j] = acc[j] * r + (float)ov[j] * mlv.y;
            M = mlv.x;
        } else {
            const float w = __expf(mlv.x - M) * mlv.y;
            denom += w;
#pragma unroll
            for (int j = 0; j < 8; j++) acc[j] += (float)ov[j] * w;
        }
    }
    const float inv = 1.0f / denom;
    half8 o;
#pragma unroll
    for (int j = 0; j < 8; j++) o[j] = (_Float16)(acc[j] * inv);
    *(half8*)(at + (size_t)qrow * DMODEL + c8) = o;
}

// ---------------- launch ----------------
extern "C" void kernel_launch(void* const* d_in, const int* in_sizes, int n_in,
                              void* d_out, int out_size, void* d_ws, size_t ws_size,
                              hipStream_t stream) {
    const float* Q  = (const float*)d_in[0];
    const float* K  = (const float*)d_in[1];
    const float* V  = (const float*)d_in[2];
    const float* Wq = (const float*)d_in[3];
    const float* bq = (const float*)d_in[4];
    const float* Wk = (const float*)d_in[5];
    const float* bk = (const float*)d_in[6];
    const float* Wv = (const float*)d_in[7];
    const float* bv = (const float*)d_in[8];
    const float* Wo = (const float*)d_in[9];
    const float* bo = (const float*)d_in[10];

    // 32 MB workspace, liveness-aliased (MB offsets):
    //  0-4  : Qh           -> Vt (after transpose)
    //  4-18 : Kh,Vh,Wqh,Wkh,Wvh  \
    // 18-22 : vh (dead after transpose) -> Opart(15.25)@4 + ml(0.95)@~19.25
    // 22-24 : Woh  [live to end]
    // 24-28 : qh           -> at (after attn; combine writes, gemm_out reads)
    // 28-32 : kh
    char* w = (char*)d_ws;
    const size_t MB = 1 << 20;
    _Float16* Qh  = (_Float16*)(w + 0 * MB);
    _Float16* Kh  = (_Float16*)(w + 4 * MB);
    _Float16* Vh  = (_Float16*)(w + 8 * MB);
    _Float16* Wqh = (_Float16*)(w + 12 * MB);
    _Float16* Wkh = (_Float16*)(w + 14 * MB);
    _Float16* Wvh = (_Float16*)(w + 16 * MB);
    _Float16* vh  = (_Float16*)(w + 18 * MB);
    _Float16* Woh = (_Float16*)(w + 22 * MB);
    _Float16* qh  = (_Float16*)(w + 24 * MB);
    _Float16* kh  = (_Float16*)(w + 28 * MB);
    _Float16* Vt    = (_Float16*)(w + 0 * MB);
    _Float16* Opart = (_Float16*)(w + 4 * MB);                 // 15,990,784 B
    float2*   ml    = (float2*)  (w + 4 * MB + 15990784);      // 999,424 B (ends ~20.2 MB < 22)
    _Float16* at    = (_Float16*)(w + 24 * MB);

    const size_t SD = (size_t)S_LEN * DMODEL;
    const size_t WD = (size_t)DMODEL * DMODEL;

    CvtArgs ca;
    ca.src[0] = Q;  ca.dst[0] = Qh;  ca.n[0] = (int)SD;
    ca.src[1] = K;  ca.dst[1] = Kh;  ca.n[1] = (int)SD;
    ca.src[2] = V;  ca.dst[2] = Vh;  ca.n[2] = (int)SD;
    ca.src[3] = Wq; ca.dst[3] = Wqh; ca.n[3] = (int)WD;
    ca.src[4] = Wk; ca.dst[4] = Wkh; ca.n[4] = (int)WD;
    ca.src[5] = Wv; ca.dst[5] = Wvh; ca.n[5] = (int)WD;
    ca.src[6] = Wo; ca.dst[6] = Woh; ca.n[6] = (int)WD;
    cvt_kernel<<<dim3(1024, 1, 7), 256, 0, stream>>>(ca);

    QKVArgs ga;
    ga.A[0] = Qh; ga.W[0] = Wqh; ga.bias[0] = bq; ga.C[0] = qh; ga.scale[0] = 0.125f;
    ga.A[1] = Kh; ga.W[1] = Wkh; ga.bias[1] = bk; ga.C[1] = kh; ga.scale[1] = 1.0f;
    ga.A[2] = Vh; ga.W[2] = Wvh; ga.bias[2] = bv; ga.C[2] = vh; ga.scale[2] = 1.0f;
    gemm_qkv<<<dim3(8, 16, 3), 256, 0, stream>>>(ga);

    transpose_v<<<dim3(32, 16), 256, 0, stream>>>(vh, Vt);

    AttnMap map;
    map.base[0] = 0;
    for (int qt = 0; qt < 16; qt++)
        map.base[qt + 1] = map.base[qt] + (2 * (qt + 1) + CHUNK - 1) / CHUNK;
    // map.base[16] == NCHUNK (61)

    attn_kernel<<<dim3(NCHUNK, NHEADS), 512, 0, stream>>>(qh, kh, Vt, Opart, ml, map);
    combine_kernel<<<dim3(1024), 256, 0, stream>>>(Opart, ml, at, map);
    gemm_out_k<<<dim3(8, 16), 256, 0, stream>>>(at, Woh, bo, (float*)d_out);
}

// Round 6
// 97.985 us; speedup vs baseline: 2.3899x; 1.1289x over previous
//
#include <hip/hip_runtime.h>
#include <hip/hip_bf16.h>
#include <stdint.h>

#define S_LEN  2048
#define DMODEL 1024
#define NHEADS 16
#define HDIM   64
#define CHUNK  7      // k-tiles (64 keys) per attention chunk-block
#define NCHUNK 46     // sum over 16 q-tiles of ceil(2*(qt+1)/CHUNK)

typedef __attribute__((ext_vector_type(8))) _Float16 half8;
typedef __attribute__((ext_vector_type(4))) _Float16 half4;
typedef __attribute__((ext_vector_type(4))) float    f32x4;

struct AttnMap { int base[17]; };

// ---------------- GEMM: C[2048][1024] = A[2048][1024] x W[1024][1024]^T + bias ----------------
// BM=128, BN=64, BK=32; 256 thr = 4 waves (2x2), wave tile 64x32 (4x2 frags).
// W is always fp32 (converted in-register while staging). A is fp32 (reg-convert)
// or fp16 (global_load_lds) per template arg. Conversion fused => no cvt pass.
__device__ __forceinline__ void gload16(const _Float16* g, _Float16* l) {
    __builtin_amdgcn_global_load_lds(
        (__attribute__((address_space(1))) void*)const_cast<_Float16*>(g),
        (__attribute__((address_space(3))) void*)l, 16, 0, 0);
}

__device__ __forceinline__ half8 cvt8(const float* s) {
    float4 v0 = *(const float4*)s;
    float4 v1 = *(const float4*)(s + 4);
    half8 o;
    o[0] = (_Float16)v0.x; o[1] = (_Float16)v0.y;
    o[2] = (_Float16)v0.z; o[3] = (_Float16)v0.w;
    o[4] = (_Float16)v1.x; o[5] = (_Float16)v1.y;
    o[6] = (_Float16)v1.z; o[7] = (_Float16)v1.w;
    return o;
}

template<bool A32, typename OT>
__device__ __forceinline__ void gemm_body(
    const void* __restrict__ Aptr,
    const float* __restrict__ W,
    const float* __restrict__ bias,
    OT* __restrict__ C, float scale)
{
    __shared__ _Float16 As[128 * 32];
    __shared__ _Float16 Bs[64 * 32];
    const int tid  = threadIdx.x;
    const int lane = tid & 63, wid = tid >> 6;
    const int row0 = blockIdx.y * 128;
    const int col0 = blockIdx.x * 64;
    const int wr = wid >> 1, wc = wid & 1;
    const int lr = lane & 15, lg = lane >> 4;

    f32x4 acc[4][2];
#pragma unroll
    for (int i = 0; i < 4; i++)
#pragma unroll
        for (int j = 0; j < 2; j++) acc[i][j] = (f32x4)(0.0f);

    for (int k0 = 0; k0 < DMODEL; k0 += 32) {
        if constexpr (A32) {
            const float* A = (const float*)Aptr;
#pragma unroll
            for (int r = 0; r < 2; r++) {   // 512 granules, 2/thread
                const int g = r * 256 + tid;
                *(half8*)(As + g * 8) =
                    cvt8(A + (size_t)(row0 + (g >> 2)) * DMODEL + k0 + (g & 3) * 8);
            }
        } else {
            const _Float16* A = (const _Float16*)Aptr;
#pragma unroll
            for (int r = 0; r < 2; r++) {
                const int g = r * 256 + wid * 64 + lane;
                gload16(A + (size_t)(row0 + (g >> 2)) * DMODEL + k0 + (g & 3) * 8,
                        As + ((size_t)r * 256 + wid * 64) * 8);
            }
        }
        {   // B: 256 granules, 1/thread, fp32 reg-convert
            const int g = tid;
            *(half8*)(Bs + g * 8) =
                cvt8(W + (size_t)(col0 + (g >> 2)) * DMODEL + k0 + (g & 3) * 8);
        }
        __syncthreads();
        half8 af[4], bf[2];
#pragma unroll
        for (int i = 0; i < 4; i++)
            af[i] = *(const half8*)(As + (wr * 64 + i * 16 + lr) * 32 + lg * 8);
#pragma unroll
        for (int j = 0; j < 2; j++)
            bf[j] = *(const half8*)(Bs + (wc * 32 + j * 16 + lr) * 32 + lg * 8);
        __builtin_amdgcn_s_setprio(1);
#pragma unroll
        for (int i = 0; i < 4; i++)
#pragma unroll
            for (int j = 0; j < 2; j++)
                acc[i][j] = __builtin_amdgcn_mfma_f32_16x16x32_f16(af[i], bf[j], acc[i][j], 0, 0, 0);
        __builtin_amdgcn_s_setprio(0);
        __syncthreads();
    }
#pragma unroll
    for (int i = 0; i < 4; i++)
#pragma unroll
        for (int j = 0; j < 2; j++) {
            const int row = row0 + wr * 64 + i * 16 + lg * 4;
            const int col = col0 + wc * 32 + j * 16 + lr;
            const float b = bias[col];
#pragma unroll
            for (int rj = 0; rj < 4; rj++) {
                float v = (acc[i][j][rj] + b) * scale;
                if constexpr (sizeof(OT) == 2)
                    C[(size_t)(row + rj) * DMODEL + col] = (OT)(_Float16)v;
                else
                    C[(size_t)(row + rj) * DMODEL + col] = v;
            }
        }
}

struct QKVArgs {
    const float* A[3];
    const float* W[3];
    const float* bias[3];
    _Float16*    C[3];
    float        scale[3];
};

__global__ __launch_bounds__(256) void gemm_qkv(QKVArgs a) {
    const int z = blockIdx.z;
    gemm_body<true, _Float16>(a.A[z], a.W[z], a.bias[z], a.C[z], a.scale[z]);
}

__global__ __launch_bounds__(256) void gemm_out_k(const _Float16* __restrict__ A,
                                                  const float* __restrict__ W,
                                                  const float* __restrict__ bias,
                                                  float* __restrict__ C) {
    gemm_body<false, float>(A, W, bias, C, 1.0f);
}

// ---------------- V transpose: v[2048][1024] -> Vt[16][64][2048] ----------------
__global__ __launch_bounds__(256) void transpose_v(const _Float16* __restrict__ v,
                                                   _Float16* __restrict__ Vt) {
    __shared__ _Float16 t[64][72];
    const int s0 = blockIdx.x * 64;
    const int h  = blockIdx.y;
    const int tid = threadIdx.x;
#pragma unroll
    for (int r = 0; r < 2; r++) {
        const int g = r * 256 + tid;
        const int sr = g >> 3, c8 = (g & 7) * 8;
        *(half8*)(&t[sr][c8]) = *(const half8*)(v + (size_t)(s0 + sr) * DMODEL + h * HDIM + c8);
    }
    __syncthreads();
#pragma unroll
    for (int r = 0; r < 2; r++) {
        const int g = r * 256 + tid;
        const int d = g >> 3, c8 = (g & 7) * 8;
        half8 o;
#pragma unroll
        for (int j = 0; j < 8; j++) o[j] = t[c8 + j][d];
        *(half8*)(Vt + (size_t)(h * HDIM + d) * S_LEN + s0 + c8) = o;
    }
}

// ---------------- causal flash attention (LDS-staged K/V, chunked split-K) ----------------
__global__ __launch_bounds__(512, 6) void attn_kernel(
    const _Float16* __restrict__ q,
    const _Float16* __restrict__ k,
    const _Float16* __restrict__ Vt,
    _Float16* __restrict__ Opart,   // [16][NCHUNK][128][64], normalized
    float2* __restrict__ ml,        // [16][NCHUNK][128]
    AttnMap map)
{
    __shared__ _Float16 Kl[2][64 * 64];
    __shared__ _Float16 Vl[2][64 * 64];
    __shared__ _Float16 P[8][16][72];
    const int tid = threadIdx.x, lane = tid & 63, wid = tid >> 6;
    const int x = NCHUNK - 1 - (int)blockIdx.x;   // heavy chunks dispatched first
    const int h = blockIdx.y;
    int qt = 0;
    while (map.base[qt + 1] <= x) qt++;
    const int c  = x - map.base[qt];
    const int q0 = qt * 128 + wid * 16;
    const int lr = lane & 15, lg = lane >> 4;
    const int srcb = lg * 20;

    const int r8 = lane >> 3, sl = lane & 7;
    const int ssw = (sl ^ r8) * 8;   // pre-swizzled source column (elements)

    half8 qf[2];
#pragma unroll
    for (int ds = 0; ds < 2; ds++)
        qf[ds] = *(const half8*)(q + (size_t)(q0 + lr) * DMODEL + h * HDIM + ds * 32 + lg * 8);

    float m = -1e30f, lsum = 0.0f;
    f32x4 od[4];
#pragma unroll
    for (int dt = 0; dt < 4; dt++) od[dt] = (f32x4)(0.0f);

    const int T2 = 2 * (qt + 1);
    const int t0 = c * CHUNK;
    const int t1 = (T2 < t0 + CHUNK) ? T2 : (t0 + CHUNK);

    auto stage = [&](int b, int t) {
        const int kb = t * 64;
        gload16(k + (size_t)(kb + wid * 8 + r8) * DMODEL + h * HDIM + ssw,
                &Kl[b][wid * 8 * 64]);
        gload16(Vt + (size_t)(h * HDIM + wid * 8 + r8) * S_LEN + kb + ssw,
                &Vl[b][wid * 8 * 64]);
    };

    int cur = 0;
    stage(0, t0);
    __syncthreads();

    for (int t = t0; t < t1; t++) {
        if (t + 1 < t1) stage(cur ^ 1, t + 1);
        const int k0 = t * 64;
        f32x4 sc[4];
#pragma unroll
        for (int kt = 0; kt < 4; kt++) sc[kt] = (f32x4)(0.0f);
        __builtin_amdgcn_s_setprio(1);
#pragma unroll
        for (int kt = 0; kt < 4; kt++)
#pragma unroll
            for (int ds = 0; ds < 2; ds++) {
                half8 kf = *(const half8*)(&Kl[cur][(kt * 16 + lr) * 64 + (((ds * 4 + lg) ^ (lr & 7)) * 8)]);
                sc[kt] = __builtin_amdgcn_mfma_f32_16x16x32_f16(kf, qf[ds], sc[kt], 0, 0, 0);  // swapped
            }
        __builtin_amdgcn_s_setprio(0);
        if (k0 + 63 > q0) {
            const int qrow = q0 + lr;
#pragma unroll
            for (int kt = 0; kt < 4; kt++) {
                const int kb2 = k0 + kt * 16 + lg * 4;
#pragma unroll
                for (int r = 0; r < 4; r++)
                    if (kb2 + r > qrow) sc[kt][r] = -1e30f;
            }
        }
        // tree max (depth ~4)
        float mk[4];
#pragma unroll
        for (int kt = 0; kt < 4; kt++)
            mk[kt] = fmaxf(fmaxf(sc[kt][0], sc[kt][1]), fmaxf(sc[kt][2], sc[kt][3]));
        float vmax = fmaxf(fmaxf(mk[0], mk[1]), fmaxf(mk[2], mk[3]));
        vmax = fmaxf(vmax, __shfl_xor(vmax, 16));
        vmax = fmaxf(vmax, __shfl_xor(vmax, 32));
        if (!__all(vmax <= m + 8.0f)) {       // T13 defer-max
            const float mnew = fmaxf(m, vmax);
            const float sfac = __expf(m - mnew);
            m = mnew;
            lsum *= sfac;
            float sf[4];
#pragma unroll
            for (int r = 0; r < 4; r++) sf[r] = __shfl(sfac, srcb + r);
#pragma unroll
            for (int dt = 0; dt < 4; dt++)
#pragma unroll
                for (int r = 0; r < 4; r++) od[dt][r] *= sf[r];
        }
        float ps[4];
#pragma unroll
        for (int kt = 0; kt < 4; kt++) {
            float p0 = __expf(sc[kt][0] - m), p1 = __expf(sc[kt][1] - m);
            float p2 = __expf(sc[kt][2] - m), p3 = __expf(sc[kt][3] - m);
            sc[kt][0] = p0; sc[kt][1] = p1; sc[kt][2] = p2; sc[kt][3] = p3;
            ps[kt] = (p0 + p1) + (p2 + p3);
        }
        float psum = (ps[0] + ps[1]) + (ps[2] + ps[3]);
        psum += __shfl_xor(psum, 16);
        psum += __shfl_xor(psum, 32);
        lsum += psum;
#pragma unroll
        for (int kt = 0; kt < 4; kt++) {
            half4 ph;
#pragma unroll
            for (int r = 0; r < 4; r++) ph[r] = (_Float16)sc[kt][r];
            *(half4*)(&P[wid][lr][kt * 16 + lg * 4]) = ph;
        }
        __builtin_amdgcn_s_setprio(1);
#pragma unroll
        for (int ks = 0; ks < 2; ks++) {
            half8 pa = *(const half8*)(&P[wid][lr][ks * 32 + lg * 8]);
#pragma unroll
            for (int dt = 0; dt < 4; dt++) {
                half8 vb = *(const half8*)(&Vl[cur][(dt * 16 + lr) * 64 + (((ks * 4 + lg) ^ (lr & 7)) * 8)]);
                od[dt] = __builtin_amdgcn_mfma_f32_16x16x32_f16(pa, vb, od[dt], 0, 0, 0);
            }
        }
        __builtin_amdgcn_s_setprio(0);
        __syncthreads();
        cur ^= 1;
    }

    const float inv = 1.0f / lsum;
    float invb[4];
#pragma unroll
    for (int r = 0; r < 4; r++) invb[r] = __shfl(inv, srcb + r);
    _Float16* Ob = Opart + ((size_t)h * NCHUNK + x) * 128 * 64;
#pragma unroll
    for (int dt = 0; dt < 4; dt++)
#pragma unroll
        for (int r = 0; r < 4; r++)
            Ob[(size_t)(wid * 16 + lg * 4 + r) * 64 + dt * 16 + lr] = (_Float16)(od[dt][r] * invb[r]);
    if (lane < 16) {
        float2 v; v.x = m; v.y = lsum;
        ml[((size_t)h * NCHUNK + x) * 128 + wid * 16 + lr] = v;
    }
}

// ---------------- chunk combine: at[q][h*64+d] fp16 ----------------
__global__ __launch_bounds__(256) void combine_kernel(
    const _Float16* __restrict__ Opart, const float2* __restrict__ ml,
    _Float16* __restrict__ at, AttnMap map)
{
    const int idx = blockIdx.x * 256 + threadIdx.x;
    const int qrow = idx >> 7;
    const int c8 = (idx & 127) * 8;
    const int h = c8 >> 6, d = c8 & 63;
    const int qt = qrow >> 7;
    const int cb = map.base[qt];
    const int nc = map.base[qt + 1] - cb;
    const int lrow = qrow & 127;

    float M = -1e30f, denom = 0.0f;
    float acc[8];
#pragma unroll
    for (int j = 0; j < 8; j++) acc[j] = 0.0f;
    for (int cc = 0; cc < nc; cc++) {
        const size_t ci = (size_t)h * NCHUNK + cb + cc;
        const float2 mlv = ml[ci * 128 + lrow];
        half8 ov = *(const half8*)(Opart + (ci * 128 + lrow) * 64 + d);
        if (mlv.x > M) {
            const float r = __expf(M - mlv.x);
            denom = denom * r + mlv.y;
#pragma unroll
            for (int j = 0; j < 8; j++) acc[j] = acc[j] * r + (float)ov[j] * mlv.y;
            M = mlv.x;
        } else {
            const float w = __expf(mlv.x - M) * mlv.y;
            denom += w;
#pragma unroll
            for (int j = 0; j < 8; j++) acc[j] += (float)ov[j] * w;
        }
    }
    const float inv = 1.0f / denom;
    half8 o;
#pragma unroll
    for (int j = 0; j < 8; j++) o[j] = (_Float16)(acc[j] * inv);
    *(half8*)(at + (size_t)qrow * DMODEL + c8) = o;
}

// ---------------- launch ----------------
extern "C" void kernel_launch(void* const* d_in, const int* in_sizes, int n_in,
                              void* d_out, int out_size, void* d_ws, size_t ws_size,
                              hipStream_t stream) {
    const float* Q  = (const float*)d_in[0];
    const float* K  = (const float*)d_in[1];
    const float* V  = (const float*)d_in[2];
    const float* Wq = (const float*)d_in[3];
    const float* bq = (const float*)d_in[4];
    const float* Wk = (const float*)d_in[5];
    const float* bk = (const float*)d_in[6];
    const float* Wv = (const float*)d_in[7];
    const float* bv = (const float*)d_in[8];
    const float* Wo = (const float*)d_in[9];
    const float* bo = (const float*)d_in[10];

    // Workspace (MB offsets), liveness-aliased:
    //  0-4 : qh   (live: gemm_qkv -> attn)
    //  4-8 : kh   (live: gemm_qkv -> attn)
    //  8-12: vh   (gemm_qkv -> transpose)  -> at (combine -> gemm_out)
    // 12-16: Vt   (transpose -> attn)
    // 16-~28.3: Opart (11.5MB) + ml (0.72MB)   (attn -> combine)
    char* w = (char*)d_ws;
    const size_t MB = 1 << 20;
    _Float16* qh = (_Float16*)(w + 0 * MB);
    _Float16* kh = (_Float16*)(w + 4 * MB);
    _Float16* vh = (_Float16*)(w + 8 * MB);
    _Float16* Vt = (_Float16*)(w + 12 * MB);
    _Float16* Opart = (_Float16*)(w + 16 * MB);
    float2*   ml = (float2*)(w + 16 * MB + (size_t)NHEADS * NCHUNK * 128 * 64 * 2);
    _Float16* at = vh;   // vh dead after transpose

    QKVArgs ga;
    ga.A[0] = Q; ga.W[0] = Wq; ga.bias[0] = bq; ga.C[0] = qh; ga.scale[0] = 0.125f;
    ga.A[1] = K; ga.W[1] = Wk; ga.bias[1] = bk; ga.C[1] = kh; ga.scale[1] = 1.0f;
    ga.A[2] = V; ga.W[2] = Wv; ga.bias[2] = bv; ga.C[2] = vh; ga.scale[2] = 1.0f;
    gemm_qkv<<<dim3(16, 16, 3), 256, 0, stream>>>(ga);

    transpose_v<<<dim3(32, 16), 256, 0, stream>>>(vh, Vt);

    AttnMap map;
    map.base[0] = 0;
    for (int qt = 0; qt < 16; qt++)
        map.base[qt + 1] = map.base[qt] + (2 * (qt + 1) + CHUNK - 1) / CHUNK;
    // map.base[16] == NCHUNK (46)

    attn_kernel<<<dim3(NCHUNK, NHEADS), 512, 0, stream>>>(qh, kh, Vt, Opart, ml, map);
    combine_kernel<<<dim3(1024), 256, 0, stream>>>(Opart, ml, at, map);
    gemm_out_k<<<dim3(16, 16), 256, 0, stream>>>(at, Wo, bo, (float*)d_out);
}

// Round 7
// 84.519 us; speedup vs baseline: 2.7707x; 1.1593x over previous
//
#include <hip/hip_runtime.h>
#include <hip/hip_bf16.h>
#include <stdint.h>

#define S_LEN  2048
#define DMODEL 1024
#define NHEADS 16
#define HDIM   64
#define CHUNK  7      // k-tiles (64 keys) per attention chunk-block
#define NCHUNK 46     // sum over 16 q-tiles of ceil(2*(qt+1)/CHUNK)

typedef __attribute__((ext_vector_type(8))) _Float16 half8;
typedef __attribute__((ext_vector_type(4))) _Float16 half4;
typedef __attribute__((ext_vector_type(4))) float    f32x4;

struct AttnMap { int base[17]; };

// ---------------- fp32 -> fp16 convert (7 tensors, one launch) ----------------
struct CvtArgs {
    const float* src[7];
    _Float16*    dst[7];
    int          n[7];
};

__global__ __launch_bounds__(256) void cvt_kernel(CvtArgs a) {
    const int z = blockIdx.z;
    const float* __restrict__ src = a.src[z];
    _Float16* __restrict__ dst = a.dst[z];
    const int n = a.n[z];
    const int stride = gridDim.x * blockDim.x * 8;
    for (int i = (blockIdx.x * blockDim.x + threadIdx.x) * 8; i < n; i += stride) {
        float4 v0 = *(const float4*)(src + i);
        float4 v1 = *(const float4*)(src + i + 4);
        half8 o;
        o[0] = (_Float16)v0.x; o[1] = (_Float16)v0.y;
        o[2] = (_Float16)v0.z; o[3] = (_Float16)v0.w;
        o[4] = (_Float16)v1.x; o[5] = (_Float16)v1.y;
        o[6] = (_Float16)v1.z; o[7] = (_Float16)v1.w;
        *(half8*)(dst + i) = o;
    }
}

// ---------------- GEMM: C[2048][1024] = A[2048][1024] x W[1024][1024]^T + bias ----------------
// BM=128, BN=64, BK=64; 256 thr = 4 waves (2x2), wave tile 64x32 (4x2 frags).
// fp16 inputs via global_load_lds. 128B LDS rows -> both-sides XOR swizzle
// (pre-swizzled global source slot, slot^(row&7); swizzled ds_read). 1-D grid
// with XCD-contiguous remap (bijective: grid%8==0).
__device__ __forceinline__ void gload16(const _Float16* g, _Float16* l) {
    __builtin_amdgcn_global_load_lds(
        (__attribute__((address_space(1))) void*)const_cast<_Float16*>(g),
        (__attribute__((address_space(3))) void*)l, 16, 0, 0);
}

template<typename OT>
__device__ __forceinline__ void gemm_body(
    const _Float16* __restrict__ A,
    const _Float16* __restrict__ W,
    const float*    __restrict__ bias,
    OT* __restrict__ C, float scale, int bx, int by)
{
    __shared__ _Float16 As[128 * 64];   // [row][slot^(row&7) granules of 8]
    __shared__ _Float16 Bs[64 * 64];
    const int tid  = threadIdx.x;
    const int lane = tid & 63, wid = tid >> 6;
    const int row0 = by * 128;
    const int col0 = bx * 64;
    const int wr = wid >> 1, wc = wid & 1;
    const int lr = lane & 15, lg = lane >> 4;
    const int sl = lane & 7;

    f32x4 acc[4][2];
#pragma unroll
    for (int i = 0; i < 4; i++)
#pragma unroll
        for (int j = 0; j < 2; j++) acc[i][j] = (f32x4)(0.0f);

    for (int k0 = 0; k0 < DMODEL; k0 += 64) {
#pragma unroll
        for (int r = 0; r < 4; r++) {       // A: 1024 granules, 4/thread
            const int base = r * 256 + wid * 64;
            const int row  = (base + lane) >> 3;
            gload16(A + (size_t)(row0 + row) * DMODEL + k0 + ((sl ^ (row & 7)) * 8),
                    As + (size_t)base * 8);
        }
#pragma unroll
        for (int r = 0; r < 2; r++) {       // B: 512 granules, 2/thread
            const int base = r * 256 + wid * 64;
            const int row  = (base + lane) >> 3;
            gload16(W + (size_t)(col0 + row) * DMODEL + k0 + ((sl ^ (row & 7)) * 8),
                    Bs + (size_t)base * 8);
        }
        __syncthreads();
#pragma unroll
        for (int ks = 0; ks < 2; ks++) {
            half8 af[4], bf[2];
#pragma unroll
            for (int i = 0; i < 4; i++)
                af[i] = *(const half8*)(As + (wr * 64 + i * 16 + lr) * 64 + (((ks * 4 + lg) ^ (lr & 7)) * 8));
#pragma unroll
            for (int j = 0; j < 2; j++)
                bf[j] = *(const half8*)(Bs + (wc * 32 + j * 16 + lr) * 64 + (((ks * 4 + lg) ^ (lr & 7)) * 8));
            __builtin_amdgcn_s_setprio(1);
#pragma unroll
            for (int i = 0; i < 4; i++)
#pragma unroll
                for (int j = 0; j < 2; j++)
                    acc[i][j] = __builtin_amdgcn_mfma_f32_16x16x32_f16(af[i], bf[j], acc[i][j], 0, 0, 0);
            __builtin_amdgcn_s_setprio(0);
        }
        __syncthreads();
    }
#pragma unroll
    for (int i = 0; i < 4; i++)
#pragma unroll
        for (int j = 0; j < 2; j++) {
            const int row = row0 + wr * 64 + i * 16 + lg * 4;
            const int col = col0 + wc * 32 + j * 16 + lr;
            const float b = bias[col];
#pragma unroll
            for (int rj = 0; rj < 4; rj++) {
                float v = (acc[i][j][rj] + b) * scale;
                if constexpr (sizeof(OT) == 2)
                    C[(size_t)(row + rj) * DMODEL + col] = (OT)(_Float16)v;
                else
                    C[(size_t)(row + rj) * DMODEL + col] = v;
            }
        }
}

struct QKVArgs {
    const _Float16* A[3];
    const _Float16* W[3];
    const float*    bias[3];
    _Float16*       C[3];
    float           scale[3];
};

// grid: 768 1-D. XCD remap -> sid; sid -> (z, by, bx) with bx fastest (A-panel reuse).
__global__ __launch_bounds__(256) void gemm_qkv(QKVArgs a) {
    const int nper = (int)gridDim.x >> 3;
    const int sid  = ((int)blockIdx.x & 7) * nper + ((int)blockIdx.x >> 3);
    const int z  = sid >> 8;
    const int r  = sid & 255;
    const int by = r >> 4, bx = r & 15;
    gemm_body<_Float16>(a.A[z], a.W[z], a.bias[z], a.C[z], a.scale[z], bx, by);
}

__global__ __launch_bounds__(256) void gemm_out_k(const _Float16* __restrict__ A,
                                                  const _Float16* __restrict__ W,
                                                  const float* __restrict__ bias,
                                                  float* __restrict__ C) {
    const int nper = (int)gridDim.x >> 3;
    const int sid  = ((int)blockIdx.x & 7) * nper + ((int)blockIdx.x >> 3);
    const int by = sid >> 4, bx = sid & 15;
    gemm_body<float>(A, W, bias, C, 1.0f, bx, by);
}

// ---------------- V transpose: v[2048][1024] -> Vt[16][64][2048] ----------------
__global__ __launch_bounds__(256) void transpose_v(const _Float16* __restrict__ v,
                                                   _Float16* __restrict__ Vt) {
    __shared__ _Float16 t[64][72];
    const int s0 = blockIdx.x * 64;
    const int h  = blockIdx.y;
    const int tid = threadIdx.x;
#pragma unroll
    for (int r = 0; r < 2; r++) {
        const int g = r * 256 + tid;
        const int sr = g >> 3, c8 = (g & 7) * 8;
        *(half8*)(&t[sr][c8]) = *(const half8*)(v + (size_t)(s0 + sr) * DMODEL + h * HDIM + c8);
    }
    __syncthreads();
#pragma unroll
    for (int r = 0; r < 2; r++) {
        const int g = r * 256 + tid;
        const int d = g >> 3, c8 = (g & 7) * 8;
        half8 o;
#pragma unroll
        for (int j = 0; j < 8; j++) o[j] = t[c8 + j][d];
        *(half8*)(Vt + (size_t)(h * HDIM + d) * S_LEN + s0 + c8) = o;
    }
}

// ---------------- causal flash attention (LDS-staged K/V, chunked split-K) ----------------
__global__ __launch_bounds__(512, 6) void attn_kernel(
    const _Float16* __restrict__ q,
    const _Float16* __restrict__ k,
    const _Float16* __restrict__ Vt,
    _Float16* __restrict__ Opart,   // [16][NCHUNK][128][64], normalized
    float2* __restrict__ ml,        // [16][NCHUNK][128]
    AttnMap map)
{
    __shared__ _Float16 Kl[2][64 * 64];
    __shared__ _Float16 Vl[2][64 * 64];
    __shared__ _Float16 P[8][16][72];
    const int tid = threadIdx.x, lane = tid & 63, wid = tid >> 6;
    const int x = NCHUNK - 1 - (int)blockIdx.x;   // heavy chunks first
    const int h = blockIdx.y;
    int qt = 0;
    while (map.base[qt + 1] <= x) qt++;
    const int c  = x - map.base[qt];
    const int q0 = qt * 128 + wid * 16;
    const int lr = lane & 15, lg = lane >> 4;
    const int srcb = lg * 20;

    const int r8 = lane >> 3, sl = lane & 7;
    const int ssw = (sl ^ r8) * 8;

    half8 qf[2];
#pragma unroll
    for (int ds = 0; ds < 2; ds++)
        qf[ds] = *(const half8*)(q + (size_t)(q0 + lr) * DMODEL + h * HDIM + ds * 32 + lg * 8);

    float m = -1e30f, lsum = 0.0f;
    f32x4 od[4];
#pragma unroll
    for (int dt = 0; dt < 4; dt++) od[dt] = (f32x4)(0.0f);

    const int T2 = 2 * (qt + 1);
    const int t0 = c * CHUNK;
    const int t1 = (T2 < t0 + CHUNK) ? T2 : (t0 + CHUNK);

    auto stage = [&](int b, int t) {
        const int kb = t * 64;
        gload16(k + (size_t)(kb + wid * 8 + r8) * DMODEL + h * HDIM + ssw,
                &Kl[b][wid * 8 * 64]);
        gload16(Vt + (size_t)(h * HDIM + wid * 8 + r8) * S_LEN + kb + ssw,
                &Vl[b][wid * 8 * 64]);
    };

    int cur = 0;
    stage(0, t0);
    __syncthreads();

    for (int t = t0; t < t1; t++) {
        if (t + 1 < t1) stage(cur ^ 1, t + 1);
        const int k0 = t * 64;
        f32x4 sc[4];
#pragma unroll
        for (int kt = 0; kt < 4; kt++) sc[kt] = (f32x4)(0.0f);
        __builtin_amdgcn_s_setprio(1);
#pragma unroll
        for (int kt = 0; kt < 4; kt++)
#pragma unroll
            for (int ds = 0; ds < 2; ds++) {
                half8 kf = *(const half8*)(&Kl[cur][(kt * 16 + lr) * 64 + (((ds * 4 + lg) ^ (lr & 7)) * 8)]);
                sc[kt] = __builtin_amdgcn_mfma_f32_16x16x32_f16(kf, qf[ds], sc[kt], 0, 0, 0);  // swapped
            }
        __builtin_amdgcn_s_setprio(0);
        if (k0 + 63 > q0) {
            const int qrow = q0 + lr;
#pragma unroll
            for (int kt = 0; kt < 4; kt++) {
                const int kb2 = k0 + kt * 16 + lg * 4;
#pragma unroll
                for (int r = 0; r < 4; r++)
                    if (kb2 + r > qrow) sc[kt][r] = -1e30f;
            }
        }
        float mk[4];
#pragma unroll
        for (int kt = 0; kt < 4; kt++)
            mk[kt] = fmaxf(fmaxf(sc[kt][0], sc[kt][1]), fmaxf(sc[kt][2], sc[kt][3]));
        float vmax = fmaxf(fmaxf(mk[0], mk[1]), fmaxf(mk[2], mk[3]));
        vmax = fmaxf(vmax, __shfl_xor(vmax, 16));
        vmax = fmaxf(vmax, __shfl_xor(vmax, 32));
        if (!__all(vmax <= m + 8.0f)) {       // T13 defer-max
            const float mnew = fmaxf(m, vmax);
            const float sfac = __expf(m - mnew);
            m = mnew;
            lsum *= sfac;
            float sf[4];
#pragma unroll
            for (int r = 0; r < 4; r++) sf[r] = __shfl(sfac, srcb + r);
#pragma unroll
            for (int dt = 0; dt < 4; dt++)
#pragma unroll
                for (int r = 0; r < 4; r++) od[dt][r] *= sf[r];
        }
        float ps[4];
#pragma unroll
        for (int kt = 0; kt < 4; kt++) {
            float p0 = __expf(sc[kt][0] - m), p1 = __expf(sc[kt][1] - m);
            float p2 = __expf(sc[kt][2] - m), p3 = __expf(sc[kt][3] - m);
            sc[kt][0] = p0; sc[kt][1] = p1; sc[kt][2] = p2; sc[kt][3] = p3;
            ps[kt] = (p0 + p1) + (p2 + p3);
        }
        float psum = (ps[0] + ps[1]) + (ps[2] + ps[3]);
        psum += __shfl_xor(psum, 16);
        psum += __shfl_xor(psum, 32);
        lsum += psum;
#pragma unroll
        for (int kt = 0; kt < 4; kt++) {
            half4 ph;
#pragma unroll
            for (int r = 0; r < 4; r++) ph[r] = (_Float16)sc[kt][r];
            *(half4*)(&P[wid][lr][kt * 16 + lg * 4]) = ph;
        }
        __builtin_amdgcn_s_setprio(1);
#pragma unroll
        for (int ks = 0; ks < 2; ks++) {
            half8 pa = *(const half8*)(&P[wid][lr][ks * 32 + lg * 8]);
#pragma unroll
            for (int dt = 0; dt < 4; dt++) {
                half8 vb = *(const half8*)(&Vl[cur][(dt * 16 + lr) * 64 + (((ks * 4 + lg) ^ (lr & 7)) * 8)]);
                od[dt] = __builtin_amdgcn_mfma_f32_16x16x32_f16(pa, vb, od[dt], 0, 0, 0);
            }
        }
        __builtin_amdgcn_s_setprio(0);
        __syncthreads();
        cur ^= 1;
    }

    const float inv = 1.0f / lsum;
    float invb[4];
#pragma unroll
    for (int r = 0; r < 4; r++) invb[r] = __shfl(inv, srcb + r);
    _Float16* Ob = Opart + ((size_t)h * NCHUNK + x) * 128 * 64;
#pragma unroll
    for (int dt = 0; dt < 4; dt++)
#pragma unroll
        for (int r = 0; r < 4; r++)
            Ob[(size_t)(wid * 16 + lg * 4 + r) * 64 + dt * 16 + lr] = (_Float16)(od[dt][r] * invb[r]);
    if (lane < 16) {
        float2 v; v.x = m; v.y = lsum;
        ml[((size_t)h * NCHUNK + x) * 128 + wid * 16 + lr] = v;
    }
}

// ---------------- chunk combine: at[q][h*64+d] fp16 ----------------
__global__ __launch_bounds__(256) void combine_kernel(
    const _Float16* __restrict__ Opart, const float2* __restrict__ ml,
    _Float16* __restrict__ at, AttnMap map)
{
    const int idx = blockIdx.x * 256 + threadIdx.x;
    const int qrow = idx >> 7;
    const int c8 = (idx & 127) * 8;
    const int h = c8 >> 6, d = c8 & 63;
    const int qt = qrow >> 7;
    const int cb = map.base[qt];
    const int nc = map.base[qt + 1] - cb;
    const int lrow = qrow & 127;

    float M = -1e30f, denom = 0.0f;
    float acc[8];
#pragma unroll
    for (int j = 0; j < 8; j++) acc[j] = 0.0f;
    for (int cc = 0; cc < nc; cc++) {
        const size_t ci = (size_t)h * NCHUNK + cb + cc;
        const float2 mlv = ml[ci * 128 + lrow];
        half8 ov = *(const half8*)(Opart + (ci * 128 + lrow) * 64 + d);
        if (mlv.x > M) {
            const float r = __expf(M - mlv.x);
            denom = denom * r + mlv.y;
#pragma unroll
            for (int j = 0; j < 8; j++) acc[j] = acc[j] * r + (float)ov[j] * mlv.y;
            M = mlv.x;
        } else {
            const float w = __expf(mlv.x - M) * mlv.y;
            denom += w;
#pragma unroll
            for (int j = 0; j < 8; j++) acc[j] += (float)ov[j] * w;
        }
    }
    const float inv = 1.0f / denom;
    half8 o;
#pragma unroll
    for (int j = 0; j < 8; j++) o[j] = (_Float16)(acc[j] * inv);
    *(half8*)(at + (size_t)qrow * DMODEL + c8) = o;
}

// ---------------- launch ----------------
extern "C" void kernel_launch(void* const* d_in, const int* in_sizes, int n_in,
                              void* d_out, int out_size, void* d_ws, size_t ws_size,
                              hipStream_t stream) {
    const float* Q  = (const float*)d_in[0];
    const float* K  = (const float*)d_in[1];
    const float* V  = (const float*)d_in[2];
    const float* Wq = (const float*)d_in[3];
    const float* bq = (const float*)d_in[4];
    const float* Wk = (const float*)d_in[5];
    const float* bk = (const float*)d_in[6];
    const float* Wv = (const float*)d_in[7];
    const float* bv = (const float*)d_in[8];
    const float* Wo = (const float*)d_in[9];
    const float* bo = (const float*)d_in[10];

    // 32 MB workspace, liveness-aliased (MB offsets):
    //  0-4 : Qh (cvt->qkv)        -> Vt (transpose->attn)
    //  4-18: Kh(4-8) Vh(8-12) Wqh(12-14) Wkh(14-16) Wvh(16-18) [dead after qkv]
    //        -> Opart(11.5)@4 + ml(0.72)@~15.5 (attn->combine)
    // 18-22: vh (qkv->transpose) -> at (combine->gemm_out)
    // 22-24: Woh [cvt->end]
    // 24-28: qh (qkv->attn)
    // 28-32: kh (qkv->attn)
    char* w = (char*)d_ws;
    const size_t MB = 1 << 20;
    _Float16* Qh  = (_Float16*)(w + 0 * MB);
    _Float16* Kh  = (_Float16*)(w + 4 * MB);
    _Float16* Vh  = (_Float16*)(w + 8 * MB);
    _Float16* Wqh = (_Float16*)(w + 12 * MB);
    _Float16* Wkh = (_Float16*)(w + 14 * MB);
    _Float16* Wvh = (_Float16*)(w + 16 * MB);
    _Float16* vh  = (_Float16*)(w + 18 * MB);
    _Float16* Woh = (_Float16*)(w + 22 * MB);
    _Float16* qh  = (_Float16*)(w + 24 * MB);
    _Float16* kh  = (_Float16*)(w + 28 * MB);
    _Float16* Vt    = (_Float16*)(w + 0 * MB);
    _Float16* Opart = (_Float16*)(w + 4 * MB);
    float2*   ml    = (float2*)(w + 4 * MB + (size_t)NHEADS * NCHUNK * 128 * 64 * 2);
    _Float16* at    = (_Float16*)(w + 18 * MB);

    const size_t SD = (size_t)S_LEN * DMODEL;
    const size_t WD = (size_t)DMODEL * DMODEL;

    CvtArgs ca;
    ca.src[0] = Q;  ca.dst[0] = Qh;  ca.n[0] = (int)SD;
    ca.src[1] = K;  ca.dst[1] = Kh;  ca.n[1] = (int)SD;
    ca.src[2] = V;  ca.dst[2] = Vh;  ca.n[2] = (int)SD;
    ca.src[3] = Wq; ca.dst[3] = Wqh; ca.n[3] = (int)WD;
    ca.src[4] = Wk; ca.dst[4] = Wkh; ca.n[4] = (int)WD;
    ca.src[5] = Wv; ca.dst[5] = Wvh; ca.n[5] = (int)WD;
    ca.src[6] = Wo; ca.dst[6] = Woh; ca.n[6] = (int)WD;
    cvt_kernel<<<dim3(1024, 1, 7), 256, 0, stream>>>(ca);

    QKVArgs ga;
    ga.A[0] = Qh; ga.W[0] = Wqh; ga.bias[0] = bq; ga.C[0] = qh; ga.scale[0] = 0.125f;
    ga.A[1] = Kh; ga.W[1] = Wkh; ga.bias[1] = bk; ga.C[1] = kh; ga.scale[1] = 1.0f;
    ga.A[2] = Vh; ga.W[2] = Wvh; ga.bias[2] = bv; ga.C[2] = vh; ga.scale[2] = 1.0f;
    gemm_qkv<<<dim3(768), 256, 0, stream>>>(ga);

    transpose_v<<<dim3(32, 16), 256, 0, stream>>>(vh, Vt);

    AttnMap map;
    map.base[0] = 0;
    for (int qt = 0; qt < 16; qt++)
        map.base[qt + 1] = map.base[qt] + (2 * (qt + 1) + CHUNK - 1) / CHUNK;

    attn_kernel<<<dim3(NCHUNK, NHEADS), 512, 0, stream>>>(qh, kh, Vt, Opart, ml, map);
    combine_kernel<<<dim3(1024), 256, 0, stream>>>(Opart, ml, at, map);
    gemm_out_k<<<dim3(256), 256, 0, stream>>>(at, Woh, bo, (float*)d_out);
}

// Round 8
// 83.696 us; speedup vs baseline: 2.7979x; 1.0098x over previous
//
#include <hip/hip_runtime.h>
#include <hip/hip_bf16.h>
#include <stdint.h>

#define S_LEN  2048
#define DMODEL 1024
#define NHEADS 16
#define HDIM   64
#define CHUNK  7      // k-tiles (64 keys) per attention chunk-block
#define NCHUNK 46     // sum over 16 q-tiles of ceil(2*(qt+1)/CHUNK)
#define LOG2E  1.4426950408889634f

typedef __attribute__((ext_vector_type(8))) _Float16 half8;
typedef __attribute__((ext_vector_type(4))) _Float16 half4;
typedef __attribute__((ext_vector_type(4))) float    f32x4;

struct AttnMap { int base[17]; };

// ---------------- fp32 -> fp16 convert (7 tensors, one launch) ----------------
struct CvtArgs {
    const float* src[7];
    _Float16*    dst[7];
    int          n[7];
};

__global__ __launch_bounds__(256) void cvt_kernel(CvtArgs a) {
    const int z = blockIdx.z;
    const float* __restrict__ src = a.src[z];
    _Float16* __restrict__ dst = a.dst[z];
    const int n = a.n[z];
    const int stride = gridDim.x * blockDim.x * 8;
    for (int i = (blockIdx.x * blockDim.x + threadIdx.x) * 8; i < n; i += stride) {
        float4 v0 = *(const float4*)(src + i);
        float4 v1 = *(const float4*)(src + i + 4);
        half8 o;
        o[0] = (_Float16)v0.x; o[1] = (_Float16)v0.y;
        o[2] = (_Float16)v0.z; o[3] = (_Float16)v0.w;
        o[4] = (_Float16)v1.x; o[5] = (_Float16)v1.y;
        o[6] = (_Float16)v1.z; o[7] = (_Float16)v1.w;
        *(half8*)(dst + i) = o;
    }
}

// ---------------- GEMM: C[2048][1024] = A x W^T + bias ----------------
// BM x 64 tile, BK=64, 256 thr = 4 waves (2x2). Double-buffered LDS, 2-phase
// pipeline (stage(t+1) issued BEFORE compute(t); ONE barrier per k-tile).
// Both-sides XOR swizzle on 128B LDS rows. XCD-contiguous 1-D grid remap.
__device__ __forceinline__ void gload16(const _Float16* g, _Float16* l) {
    __builtin_amdgcn_global_load_lds(
        (__attribute__((address_space(1))) void*)const_cast<_Float16*>(g),
        (__attribute__((address_space(3))) void*)l, 16, 0, 0);
}

template<int BM, typename OT>
__device__ __forceinline__ void gemm_body(
    const _Float16* __restrict__ A,
    const _Float16* __restrict__ W,
    const float*    __restrict__ bias,
    OT* __restrict__ C, float scale, int bx, int by)
{
    constexpr int FI = BM / 32;            // row frags per wave (4 @BM=128, 2 @BM=64)
    __shared__ _Float16 As[2][BM * 64];
    __shared__ _Float16 Bs[2][64 * 64];
    const int tid  = threadIdx.x;
    const int lane = tid & 63, wid = tid >> 6;
    const int row0 = by * BM;
    const int col0 = bx * 64;
    const int wr = wid >> 1, wc = wid & 1;
    const int lr = lane & 15, lg = lane >> 4;
    const int sl = lane & 7;

    f32x4 acc[FI][2];
#pragma unroll
    for (int i = 0; i < FI; i++)
#pragma unroll
        for (int j = 0; j < 2; j++) acc[i][j] = (f32x4)(0.0f);

    auto stage = [&](int b, int k0) {
#pragma unroll
        for (int r = 0; r < BM / 32; r++) {     // A granules: BM*8 total
            const int base = r * 256 + wid * 64;
            const int row  = (base + lane) >> 3;
            gload16(A + (size_t)(row0 + row) * DMODEL + k0 + ((sl ^ (row & 7)) * 8),
                    &As[b][(size_t)base * 8]);
        }
#pragma unroll
        for (int r = 0; r < 2; r++) {           // B granules: 512 total
            const int base = r * 256 + wid * 64;
            const int row  = (base + lane) >> 3;
            gload16(W + (size_t)(col0 + row) * DMODEL + k0 + ((sl ^ (row & 7)) * 8),
                    &Bs[b][(size_t)base * 8]);
        }
    };

    stage(0, 0);
    __syncthreads();
    int cur = 0;
    for (int t = 0; t < DMODEL / 64; t++) {
        if (t + 1 < DMODEL / 64) stage(cur ^ 1, (t + 1) * 64);
#pragma unroll
        for (int ks = 0; ks < 2; ks++) {
            half8 af[FI], bf[2];
#pragma unroll
            for (int i = 0; i < FI; i++)
                af[i] = *(const half8*)(&As[cur][(wr * (BM / 2) + i * 16 + lr) * 64 + (((ks * 4 + lg) ^ (lr & 7)) * 8)]);
#pragma unroll
            for (int j = 0; j < 2; j++)
                bf[j] = *(const half8*)(&Bs[cur][(wc * 32 + j * 16 + lr) * 64 + (((ks * 4 + lg) ^ (lr & 7)) * 8)]);
            __builtin_amdgcn_s_setprio(1);
#pragma unroll
            for (int i = 0; i < FI; i++)
#pragma unroll
                for (int j = 0; j < 2; j++)
                    acc[i][j] = __builtin_amdgcn_mfma_f32_16x16x32_f16(af[i], bf[j], acc[i][j], 0, 0, 0);
            __builtin_amdgcn_s_setprio(0);
        }
        __syncthreads();   // stage(cur^1) landed; all waves done reading cur
        cur ^= 1;
    }
#pragma unroll
    for (int i = 0; i < FI; i++)
#pragma unroll
        for (int j = 0; j < 2; j++) {
            const int row = row0 + wr * (BM / 2) + i * 16 + lg * 4;
            const int col = col0 + wc * 32 + j * 16 + lr;
            const float b = bias[col];
#pragma unroll
            for (int rj = 0; rj < 4; rj++) {
                float v = (acc[i][j][rj] + b) * scale;
                if constexpr (sizeof(OT) == 2)
                    C[(size_t)(row + rj) * DMODEL + col] = (OT)(_Float16)v;
                else
                    C[(size_t)(row + rj) * DMODEL + col] = v;
            }
        }
}

struct QKVArgs {
    const _Float16* A[3];
    const _Float16* W[3];
    const float*    bias[3];
    _Float16*       C[3];
    float           scale[3];
};

// grid 768: XCD remap -> sid; sid -> (z, by, bx), bx fastest (A-panel L2 reuse).
__global__ __launch_bounds__(256) void gemm_qkv(QKVArgs a) {
    const int nper = (int)gridDim.x >> 3;
    const int sid  = ((int)blockIdx.x & 7) * nper + ((int)blockIdx.x >> 3);
    const int z  = sid >> 8;
    const int r  = sid & 255;
    const int by = r >> 4, bx = r & 15;
    gemm_body<128, _Float16>(a.A[z], a.W[z], a.bias[z], a.C[z], a.scale[z], bx, by);
}

// grid 512 (BM=64): 2 blocks/CU.
__global__ __launch_bounds__(256) void gemm_out_k(const _Float16* __restrict__ A,
                                                  const _Float16* __restrict__ W,
                                                  const float* __restrict__ bias,
                                                  float* __restrict__ C) {
    const int nper = (int)gridDim.x >> 3;
    const int sid  = ((int)blockIdx.x & 7) * nper + ((int)blockIdx.x >> 3);
    const int by = sid >> 4, bx = sid & 15;
    gemm_body<64, float>(A, W, bias, C, 1.0f, bx, by);
}

// ---------------- V transpose: v[2048][1024] -> Vt[16][64][2048] ----------------
__global__ __launch_bounds__(256) void transpose_v(const _Float16* __restrict__ v,
                                                   _Float16* __restrict__ Vt) {
    __shared__ _Float16 t[64][72];
    const int s0 = blockIdx.x * 64;
    const int h  = blockIdx.y;
    const int tid = threadIdx.x;
#pragma unroll
    for (int r = 0; r < 2; r++) {
        const int g = r * 256 + tid;
        const int sr = g >> 3, c8 = (g & 7) * 8;
        *(half8*)(&t[sr][c8]) = *(const half8*)(v + (size_t)(s0 + sr) * DMODEL + h * HDIM + c8);
    }
    __syncthreads();
#pragma unroll
    for (int r = 0; r < 2; r++) {
        const int g = r * 256 + tid;
        const int d = g >> 3, c8 = (g & 7) * 8;
        half8 o;
#pragma unroll
        for (int j = 0; j < 8; j++) o[j] = t[c8 + j][d];
        *(half8*)(Vt + (size_t)(h * HDIM + d) * S_LEN + s0 + c8) = o;
    }
}

// ---------------- causal flash attention (LDS-staged K/V, chunked split-K) ----------------
// exp2 domain: q pre-scaled by 0.125*log2(e); all exps are exp2f (= v_exp_f32).
__global__ __launch_bounds__(512, 6) void attn_kernel(
    const _Float16* __restrict__ q,
    const _Float16* __restrict__ k,
    const _Float16* __restrict__ Vt,
    _Float16* __restrict__ Opart,   // [16][NCHUNK][128][64], normalized
    float2* __restrict__ ml,        // [16][NCHUNK][128]  (m in log2 units, l)
    AttnMap map)
{
    __shared__ _Float16 Kl[2][64 * 64];
    __shared__ _Float16 Vl[2][64 * 64];
    __shared__ _Float16 P[8][16][72];
    const int tid = threadIdx.x, lane = tid & 63, wid = tid >> 6;
    const int x = NCHUNK - 1 - (int)blockIdx.x;   // heavy chunks first
    const int h = blockIdx.y;
    int qt = 0;
    while (map.base[qt + 1] <= x) qt++;
    const int c  = x - map.base[qt];
    const int q0 = qt * 128 + wid * 16;
    const int lr = lane & 15, lg = lane >> 4;
    const int srcb = lg * 20;

    const int r8 = lane >> 3, sl = lane & 7;
    const int ssw = (sl ^ r8) * 8;

    half8 qf[2];
#pragma unroll
    for (int ds = 0; ds < 2; ds++)
        qf[ds] = *(const half8*)(q + (size_t)(q0 + lr) * DMODEL + h * HDIM + ds * 32 + lg * 8);

    float m = -1e30f, lsum = 0.0f;
    f32x4 od[4];
#pragma unroll
    for (int dt = 0; dt < 4; dt++) od[dt] = (f32x4)(0.0f);

    const int T2 = 2 * (qt + 1);
    const int t0 = c * CHUNK;
    const int t1 = (T2 < t0 + CHUNK) ? T2 : (t0 + CHUNK);

    auto stage = [&](int b, int t) {
        const int kb = t * 64;
        gload16(k + (size_t)(kb + wid * 8 + r8) * DMODEL + h * HDIM + ssw,
                &Kl[b][wid * 8 * 64]);
        gload16(Vt + (size_t)(h * HDIM + wid * 8 + r8) * S_LEN + kb + ssw,
                &Vl[b][wid * 8 * 64]);
    };

    int cur = 0;
    stage(0, t0);
    __syncthreads();

    for (int t = t0; t < t1; t++) {
        if (t + 1 < t1) stage(cur ^ 1, t + 1);
        const int k0 = t * 64;
        f32x4 sc[4];
#pragma unroll
        for (int kt = 0; kt < 4; kt++) sc[kt] = (f32x4)(0.0f);
        __builtin_amdgcn_s_setprio(1);
#pragma unroll
        for (int kt = 0; kt < 4; kt++)
#pragma unroll
            for (int ds = 0; ds < 2; ds++) {
                half8 kf = *(const half8*)(&Kl[cur][(kt * 16 + lr) * 64 + (((ds * 4 + lg) ^ (lr & 7)) * 8)]);
                sc[kt] = __builtin_amdgcn_mfma_f32_16x16x32_f16(kf, qf[ds], sc[kt], 0, 0, 0);  // swapped
            }
        __builtin_amdgcn_s_setprio(0);
        if (k0 + 63 > q0) {
            const int qrow = q0 + lr;
#pragma unroll
            for (int kt = 0; kt < 4; kt++) {
                const int kb2 = k0 + kt * 16 + lg * 4;
#pragma unroll
                for (int r = 0; r < 4; r++)
                    if (kb2 + r > qrow) sc[kt][r] = -1e30f;
            }
        }
        float mk[4];
#pragma unroll
        for (int kt = 0; kt < 4; kt++)
            mk[kt] = fmaxf(fmaxf(sc[kt][0], sc[kt][1]), fmaxf(sc[kt][2], sc[kt][3]));
        float vmax = fmaxf(fmaxf(mk[0], mk[1]), fmaxf(mk[2], mk[3]));
        vmax = fmaxf(vmax, __shfl_xor(vmax, 16));
        vmax = fmaxf(vmax, __shfl_xor(vmax, 32));
        if (!__all(vmax <= m + 8.0f)) {       // T13 defer-max (P bounded by 2^8)
            const float mnew = fmaxf(m, vmax);
            const float sfac = exp2f(m - mnew);
            m = mnew;
            lsum *= sfac;
            float sf[4];
#pragma unroll
            for (int r = 0; r < 4; r++) sf[r] = __shfl(sfac, srcb + r);
#pragma unroll
            for (int dt = 0; dt < 4; dt++)
#pragma unroll
                for (int r = 0; r < 4; r++) od[dt][r] *= sf[r];
        }
        float ps[4];
#pragma unroll
        for (int kt = 0; kt < 4; kt++) {
            float p0 = exp2f(sc[kt][0] - m), p1 = exp2f(sc[kt][1] - m);
            float p2 = exp2f(sc[kt][2] - m), p3 = exp2f(sc[kt][3] - m);
            sc[kt][0] = p0; sc[kt][1] = p1; sc[kt][2] = p2; sc[kt][3] = p3;
            ps[kt] = (p0 + p1) + (p2 + p3);
        }
        float psum = (ps[0] + ps[1]) + (ps[2] + ps[3]);
        psum += __shfl_xor(psum, 16);
        psum += __shfl_xor(psum, 32);
        lsum += psum;
#pragma unroll
        for (int kt = 0; kt < 4; kt++) {
            half4 ph;
#pragma unroll
            for (int r = 0; r < 4; r++) ph[r] = (_Float16)sc[kt][r];
            *(half4*)(&P[wid][lr][kt * 16 + lg * 4]) = ph;
        }
        __builtin_amdgcn_s_setprio(1);
#pragma unroll
        for (int ks = 0; ks < 2; ks++) {
            half8 pa = *(const half8*)(&P[wid][lr][ks * 32 + lg * 8]);
#pragma unroll
            for (int dt = 0; dt < 4; dt++) {
                half8 vb = *(const half8*)(&Vl[cur][(dt * 16 + lr) * 64 + (((ks * 4 + lg) ^ (lr & 7)) * 8)]);
                od[dt] = __builtin_amdgcn_mfma_f32_16x16x32_f16(pa, vb, od[dt], 0, 0, 0);
            }
        }
        __builtin_amdgcn_s_setprio(0);
        __syncthreads();
        cur ^= 1;
    }

    const float inv = 1.0f / lsum;
    float invb[4];
#pragma unroll
    for (int r = 0; r < 4; r++) invb[r] = __shfl(inv, srcb + r);
    _Float16* Ob = Opart + ((size_t)h * NCHUNK + x) * 128 * 64;
#pragma unroll
    for (int dt = 0; dt < 4; dt++)
#pragma unroll
        for (int r = 0; r < 4; r++)
            Ob[(size_t)(wid * 16 + lg * 4 + r) * 64 + dt * 16 + lr] = (_Float16)(od[dt][r] * invb[r]);
    if (lane < 16) {
        float2 v; v.x = m; v.y = lsum;
        ml[((size_t)h * NCHUNK + x) * 128 + wid * 16 + lr] = v;
    }
}

// ---------------- chunk combine: at[q][h*64+d] fp16 ----------------
__global__ __launch_bounds__(256) void combine_kernel(
    const _Float16* __restrict__ Opart, const float2* __restrict__ ml,
    _Float16* __restrict__ at, AttnMap map)
{
    const int idx = blockIdx.x * 256 + threadIdx.x;
    const int qrow = idx >> 7;
    const int c8 = (idx & 127) * 8;
    const int h = c8 >> 6, d = c8 & 63;
    const int qt = qrow >> 7;
    const int cb = map.base[qt];
    const int nc = map.base[qt + 1] - cb;
    const int lrow = qrow & 127;

    float M = -1e30f, denom = 0.0f;
    float acc[8];
#pragma unroll
    for (int j = 0; j < 8; j++) acc[j] = 0.0f;
    for (int cc = 0; cc < nc; cc++) {
        const size_t ci = (size_t)h * NCHUNK + cb + cc;
        const float2 mlv = ml[ci * 128 + lrow];
        half8 ov = *(const half8*)(Opart + (ci * 128 + lrow) * 64 + d);
        if (mlv.x > M) {
            const float r = exp2f(M - mlv.x);
            denom = denom * r + mlv.y;
#pragma unroll
            for (int j = 0; j < 8; j++) acc[j] = acc[j] * r + (float)ov[j] * mlv.y;
            M = mlv.x;
        } else {
            const float w = exp2f(mlv.x - M) * mlv.y;
            denom += w;
#pragma unroll
            for (int j = 0; j < 8; j++) acc[j] += (float)ov[j] * w;
        }
    }
    const float inv = 1.0f / denom;
    half8 o;
#pragma unroll
    for (int j = 0; j < 8; j++) o[j] = (_Float16)(acc[j] * inv);
    *(half8*)(at + (size_t)qrow * DMODEL + c8) = o;
}

// ---------------- launch ----------------
extern "C" void kernel_launch(void* const* d_in, const int* in_sizes, int n_in,
                              void* d_out, int out_size, void* d_ws, size_t ws_size,
                              hipStream_t stream) {
    const float* Q  = (const float*)d_in[0];
    const float* K  = (const float*)d_in[1];
    const float* V  = (const float*)d_in[2];
    const float* Wq = (const float*)d_in[3];
    const float* bq = (const float*)d_in[4];
    const float* Wk = (const float*)d_in[5];
    const float* bk = (const float*)d_in[6];
    const float* Wv = (const float*)d_in[7];
    const float* bv = (const float*)d_in[8];
    const float* Wo = (const float*)d_in[9];
    const float* bo = (const float*)d_in[10];

    // 32 MB workspace, liveness-aliased (MB offsets):
    //  0-4 : Qh (cvt->qkv)        -> Vt (transpose->attn)
    //  4-18: Kh(4-8) Vh(8-12) Wqh(12-14) Wkh(14-16) Wvh(16-18) [dead after qkv]
    //        -> Opart(11.5)@4 + ml(0.72)@~15.5 (attn->combine)
    // 18-22: vh (qkv->transpose) -> at (combine->gemm_out)
    // 22-24: Woh [cvt->end]
    // 24-28: qh (qkv->attn)
    // 28-32: kh (qkv->attn)
    char* w = (char*)d_ws;
    const size_t MB = 1 << 20;
    _Float16* Qh  = (_Float16*)(w + 0 * MB);
    _Float16* Kh  = (_Float16*)(w + 4 * MB);
    _Float16* Vh  = (_Float16*)(w + 8 * MB);
    _Float16* Wqh = (_Float16*)(w + 12 * MB);
    _Float16* Wkh = (_Float16*)(w + 14 * MB);
    _Float16* Wvh = (_Float16*)(w + 16 * MB);
    _Float16* vh  = (_Float16*)(w + 18 * MB);
    _Float16* Woh = (_Float16*)(w + 22 * MB);
    _Float16* qh  = (_Float16*)(w + 24 * MB);
    _Float16* kh  = (_Float16*)(w + 28 * MB);
    _Float16* Vt    = (_Float16*)(w + 0 * MB);
    _Float16* Opart = (_Float16*)(w + 4 * MB);
    float2*   ml    = (float2*)(w + 4 * MB + (size_t)NHEADS * NCHUNK * 128 * 64 * 2);
    _Float16* at    = (_Float16*)(w + 18 * MB);

    const size_t SD = (size_t)S_LEN * DMODEL;
    const size_t WD = (size_t)DMODEL * DMODEL;

    CvtArgs ca;
    ca.src[0] = Q;  ca.dst[0] = Qh;  ca.n[0] = (int)SD;
    ca.src[1] = K;  ca.dst[1] = Kh;  ca.n[1] = (int)SD;
    ca.src[2] = V;  ca.dst[2] = Vh;  ca.n[2] = (int)SD;
    ca.src[3] = Wq; ca.dst[3] = Wqh; ca.n[3] = (int)WD;
    ca.src[4] = Wk; ca.dst[4] = Wkh; ca.n[4] = (int)WD;
    ca.src[5] = Wv; ca.dst[5] = Wvh; ca.n[5] = (int)WD;
    ca.src[6] = Wo; ca.dst[6] = Woh; ca.n[6] = (int)WD;
    cvt_kernel<<<dim3(1024, 1, 7), 256, 0, stream>>>(ca);

    QKVArgs ga;
    ga.A[0] = Qh; ga.W[0] = Wqh; ga.bias[0] = bq; ga.C[0] = qh; ga.scale[0] = 0.125f * LOG2E;
    ga.A[1] = Kh; ga.W[1] = Wkh; ga.bias[1] = bk; ga.C[1] = kh; ga.scale[1] = 1.0f;
    ga.A[2] = Vh; ga.W[2] = Wvh; ga.bias[2] = bv; ga.C[2] = vh; ga.scale[2] = 1.0f;
    gemm_qkv<<<dim3(768), 256, 0, stream>>>(ga);

    transpose_v<<<dim3(32, 16), 256, 0, stream>>>(vh, Vt);

    AttnMap map;
    map.base[0] = 0;
    for (int qt = 0; qt < 16; qt++)
        map.base[qt + 1] = map.base[qt] + (2 * (qt + 1) + CHUNK - 1) / CHUNK;

    attn_kernel<<<dim3(NCHUNK, NHEADS), 512, 0, stream>>>(qh, kh, Vt, Opart, ml, map);
    combine_kernel<<<dim3(1024), 256, 0, stream>>>(Opart, ml, at, map);
    gemm_out_k<<<dim3(512), 256, 0, stream>>>(at, Woh, bo, (float*)d_out);
}

// Round 9
// 79.610 us; speedup vs baseline: 2.9415x; 1.0513x over previous
//
#include <hip/hip_runtime.h>
#include <hip/hip_bf16.h>
#include <stdint.h>

#define S_LEN  2048
#define DMODEL 1024
#define NHEADS 16
#define HDIM   64
#define CHUNK  5      // k-tiles (64 keys) per attention chunk-block
#define NCHUNK 32     // sum over 8 q-tiles (256 rows) of ceil(4*(qt+1)/CHUNK)
#define LOG2E  1.4426950408889634f

typedef __attribute__((ext_vector_type(8))) _Float16 half8;
typedef __attribute__((ext_vector_type(4))) _Float16 half4;
typedef __attribute__((ext_vector_type(4))) float    f32x4;

struct AttnMap { int base[9]; };

// ---------------- fp32 -> fp16 convert (7 tensors, one launch) ----------------
struct CvtArgs {
    const float* src[7];
    _Float16*    dst[7];
    int          n[7];
};

__global__ __launch_bounds__(256) void cvt_kernel(CvtArgs a) {
    const int z = blockIdx.z;
    const float* __restrict__ src = a.src[z];
    _Float16* __restrict__ dst = a.dst[z];
    const int n = a.n[z];
    const int stride = gridDim.x * blockDim.x * 8;
    for (int i = (blockIdx.x * blockDim.x + threadIdx.x) * 8; i < n; i += stride) {
        float4 v0 = *(const float4*)(src + i);
        float4 v1 = *(const float4*)(src + i + 4);
        half8 o;
        o[0] = (_Float16)v0.x; o[1] = (_Float16)v0.y;
        o[2] = (_Float16)v0.z; o[3] = (_Float16)v0.w;
        o[4] = (_Float16)v1.x; o[5] = (_Float16)v1.y;
        o[6] = (_Float16)v1.z; o[7] = (_Float16)v1.w;
        *(half8*)(dst + i) = o;
    }
}

// ---------------- GEMM: C[2048][1024] = A x W^T + bias ----------------
// BM x 64 tile, BK=64, 4 waves (2x2). Double-buffered LDS, 2-phase pipeline.
// Both-sides XOR swizzle on 128B LDS rows. XCD-contiguous 1-D grid remap.
// TRANS output mode writes C^T (fused V transpose: Vt[col][row], half4 rows).
__device__ __forceinline__ void gload16(const _Float16* g, _Float16* l) {
    __builtin_amdgcn_global_load_lds(
        (__attribute__((address_space(1))) void*)const_cast<_Float16*>(g),
        (__attribute__((address_space(3))) void*)l, 16, 0, 0);
}

template<int BM, typename OT>
__device__ __forceinline__ void gemm_body(
    const _Float16* __restrict__ A,
    const _Float16* __restrict__ W,
    const float*    __restrict__ bias,
    OT* __restrict__ C, float scale, int bx, int by, bool trans)
{
    constexpr int FI = BM / 32;
    __shared__ _Float16 As[2][BM * 64];
    __shared__ _Float16 Bs[2][64 * 64];
    const int tid  = threadIdx.x;
    const int lane = tid & 63, wid = tid >> 6;
    const int row0 = by * BM;
    const int col0 = bx * 64;
    const int wr = wid >> 1, wc = wid & 1;
    const int lr = lane & 15, lg = lane >> 4;
    const int sl = lane & 7;

    f32x4 acc[FI][2];
#pragma unroll
    for (int i = 0; i < FI; i++)
#pragma unroll
        for (int j = 0; j < 2; j++) acc[i][j] = (f32x4)(0.0f);

    auto stage = [&](int b, int k0) {
#pragma unroll
        for (int r = 0; r < BM / 32; r++) {
            const int base = r * 256 + wid * 64;
            const int row  = (base + lane) >> 3;
            gload16(A + (size_t)(row0 + row) * DMODEL + k0 + ((sl ^ (row & 7)) * 8),
                    &As[b][(size_t)base * 8]);
        }
#pragma unroll
        for (int r = 0; r < 2; r++) {
            const int base = r * 256 + wid * 64;
            const int row  = (base + lane) >> 3;
            gload16(W + (size_t)(col0 + row) * DMODEL + k0 + ((sl ^ (row & 7)) * 8),
                    &Bs[b][(size_t)base * 8]);
        }
    };

    stage(0, 0);
    __syncthreads();
    int cur = 0;
    for (int t = 0; t < DMODEL / 64; t++) {
        if (t + 1 < DMODEL / 64) stage(cur ^ 1, (t + 1) * 64);
#pragma unroll
        for (int ks = 0; ks < 2; ks++) {
            half8 af[FI], bf[2];
#pragma unroll
            for (int i = 0; i < FI; i++)
                af[i] = *(const half8*)(&As[cur][(wr * (BM / 2) + i * 16 + lr) * 64 + (((ks * 4 + lg) ^ (lr & 7)) * 8)]);
#pragma unroll
            for (int j = 0; j < 2; j++)
                bf[j] = *(const half8*)(&Bs[cur][(wc * 32 + j * 16 + lr) * 64 + (((ks * 4 + lg) ^ (lr & 7)) * 8)]);
            __builtin_amdgcn_s_setprio(1);
#pragma unroll
            for (int i = 0; i < FI; i++)
#pragma unroll
                for (int j = 0; j < 2; j++)
                    acc[i][j] = __builtin_amdgcn_mfma_f32_16x16x32_f16(af[i], bf[j], acc[i][j], 0, 0, 0);
            __builtin_amdgcn_s_setprio(0);
        }
        __syncthreads();
        cur ^= 1;
    }
#pragma unroll
    for (int i = 0; i < FI; i++)
#pragma unroll
        for (int j = 0; j < 2; j++) {
            const int row = row0 + wr * (BM / 2) + i * 16 + lg * 4;
            const int col = col0 + wc * 32 + j * 16 + lr;
            const float b = bias[col];
            if (trans) {   // fused transpose: C^T[col][row..row+3] (fp16 only)
                half4 h;
#pragma unroll
                for (int rj = 0; rj < 4; rj++) h[rj] = (_Float16)((acc[i][j][rj] + b) * scale);
                *(half4*)((_Float16*)C + (size_t)col * S_LEN + row) = h;
            } else {
#pragma unroll
                for (int rj = 0; rj < 4; rj++) {
                    float v = (acc[i][j][rj] + b) * scale;
                    if constexpr (sizeof(OT) == 2)
                        C[(size_t)(row + rj) * DMODEL + col] = (OT)(_Float16)v;
                    else
                        C[(size_t)(row + rj) * DMODEL + col] = v;
                }
            }
        }
}

struct QKVArgs {
    const _Float16* A[3];
    const _Float16* W[3];
    const float*    bias[3];
    _Float16*       C[3];
    float           scale[3];
};

// grid 768: XCD remap -> sid; sid -> (z, by, bx), bx fastest (A-panel L2 reuse).
// z==2 (v projection) writes transposed -> Vt directly (no transpose kernel).
__global__ __launch_bounds__(256) void gemm_qkv(QKVArgs a) {
    const int nper = (int)gridDim.x >> 3;
    const int sid  = ((int)blockIdx.x & 7) * nper + ((int)blockIdx.x >> 3);
    const int z  = sid >> 8;
    const int r  = sid & 255;
    const int by = r >> 4, bx = r & 15;
    gemm_body<128, _Float16>(a.A[z], a.W[z], a.bias[z], a.C[z], a.scale[z], bx, by, z == 2);
}

__global__ __launch_bounds__(256) void gemm_out_k(const _Float16* __restrict__ A,
                                                  const _Float16* __restrict__ W,
                                                  const float* __restrict__ bias,
                                                  float* __restrict__ C) {
    const int nper = (int)gridDim.x >> 3;
    const int sid  = ((int)blockIdx.x & 7) * nper + ((int)blockIdx.x >> 3);
    const int by = sid >> 4, bx = sid & 15;
    gemm_body<64, float>(A, W, bias, C, 1.0f, bx, by, false);
}

// ---------------- causal flash attention ----------------
// grid (NCHUNK, 16), 512 thr = 8 waves x 32 q-rows (q-tile = 256 rows).
// Each K/V ds_read feeds TWO MFMAs (q-row sets lr and 16+lr) -> LDS traffic
// per unit work halved vs 16-row waves. LDS-staged K/V double-buffered via
// global_load_lds w/ pre-swizzled source. Swapped mfma(K,Q), exp2 domain,
// defer-max THR=8. Normalized fp16 partials + (m,l) per chunk.
__global__ __launch_bounds__(512, 4) void attn_kernel(
    const _Float16* __restrict__ q,
    const _Float16* __restrict__ k,
    const _Float16* __restrict__ Vt,
    _Float16* __restrict__ Opart,   // [16][NCHUNK][256][64], normalized
    float2* __restrict__ ml,        // [16][NCHUNK][256]
    AttnMap map)
{
    __shared__ _Float16 Kl[2][64 * 64];
    __shared__ _Float16 Vl[2][64 * 64];
    __shared__ _Float16 P[8][32][72];
    const int tid = threadIdx.x, lane = tid & 63, wid = tid >> 6;
    const int x = NCHUNK - 1 - (int)blockIdx.x;   // heavy chunks first
    const int h = blockIdx.y;
    int qt = 0;
    while (map.base[qt + 1] <= x) qt++;
    const int c  = x - map.base[qt];
    const int q0 = qt * 256 + wid * 32;
    const int lr = lane & 15, lg = lane >> 4;
    const int srcb = lg * 20;

    const int r8 = lane >> 3, sl = lane & 7;
    const int ssw = (sl ^ r8) * 8;

    half8 qf[2][2];
#pragma unroll
    for (int qs = 0; qs < 2; qs++)
#pragma unroll
        for (int ds = 0; ds < 2; ds++)
            qf[qs][ds] = *(const half8*)(q + (size_t)(q0 + qs * 16 + lr) * DMODEL + h * HDIM + ds * 32 + lg * 8);

    float m[2] = {-1e30f, -1e30f}, lsum[2] = {0.0f, 0.0f};
    f32x4 od[2][4];
#pragma unroll
    for (int qs = 0; qs < 2; qs++)
#pragma unroll
        for (int dt = 0; dt < 4; dt++) od[qs][dt] = (f32x4)(0.0f);

    const int T4 = 4 * (qt + 1);
    const int t0 = c * CHUNK;
    const int t1 = (T4 < t0 + CHUNK) ? T4 : (t0 + CHUNK);

    auto stage = [&](int b, int t) {
        const int kb = t * 64;
        gload16(k + (size_t)(kb + wid * 8 + r8) * DMODEL + h * HDIM + ssw,
                &Kl[b][wid * 8 * 64]);
        gload16(Vt + (size_t)(h * HDIM + wid * 8 + r8) * S_LEN + kb + ssw,
                &Vl[b][wid * 8 * 64]);
    };

    int cur = 0;
    stage(0, t0);
    __syncthreads();

    for (int t = t0; t < t1; t++) {
        if (t + 1 < t1) stage(cur ^ 1, t + 1);
        const int k0 = t * 64;
        f32x4 sc[2][4];
#pragma unroll
        for (int qs = 0; qs < 2; qs++)
#pragma unroll
            for (int kt = 0; kt < 4; kt++) sc[qs][kt] = (f32x4)(0.0f);
        __builtin_amdgcn_s_setprio(1);
#pragma unroll
        for (int kt = 0; kt < 4; kt++)
#pragma unroll
            for (int ds = 0; ds < 2; ds++) {
                half8 kf = *(const half8*)(&Kl[cur][(kt * 16 + lr) * 64 + (((ds * 4 + lg) ^ (lr & 7)) * 8)]);
                sc[0][kt] = __builtin_amdgcn_mfma_f32_16x16x32_f16(kf, qf[0][ds], sc[0][kt], 0, 0, 0);
                sc[1][kt] = __builtin_amdgcn_mfma_f32_16x16x32_f16(kf, qf[1][ds], sc[1][kt], 0, 0, 0);
            }
        __builtin_amdgcn_s_setprio(0);
        // sc[qs][kt][r] = S[key=k0+kt*16+lg*4+r][q=q0+qs*16+lr]
        if (k0 + 63 > q0) {
#pragma unroll
            for (int qs = 0; qs < 2; qs++) {
                const int qrow = q0 + qs * 16 + lr;
#pragma unroll
                for (int kt = 0; kt < 4; kt++) {
                    const int kb2 = k0 + kt * 16 + lg * 4;
#pragma unroll
                    for (int r = 0; r < 4; r++)
                        if (kb2 + r > qrow) sc[qs][kt][r] = -1e30f;
                }
            }
        }
        float vmax[2];
#pragma unroll
        for (int qs = 0; qs < 2; qs++) {
            float mk[4];
#pragma unroll
            for (int kt = 0; kt < 4; kt++)
                mk[kt] = fmaxf(fmaxf(sc[qs][kt][0], sc[qs][kt][1]), fmaxf(sc[qs][kt][2], sc[qs][kt][3]));
            float v = fmaxf(fmaxf(mk[0], mk[1]), fmaxf(mk[2], mk[3]));
            v = fmaxf(v, __shfl_xor(v, 16));
            v = fmaxf(v, __shfl_xor(v, 32));
            vmax[qs] = v;
        }
        if (!__all(vmax[0] <= m[0] + 8.0f && vmax[1] <= m[1] + 8.0f)) {   // T13
#pragma unroll
            for (int qs = 0; qs < 2; qs++) {
                const float mnew = fmaxf(m[qs], vmax[qs]);
                const float sfac = exp2f(m[qs] - mnew);
                m[qs] = mnew;
                lsum[qs] *= sfac;
                float sf[4];
#pragma unroll
                for (int r = 0; r < 4; r++) sf[r] = __shfl(sfac, srcb + r);
#pragma unroll
                for (int dt = 0; dt < 4; dt++)
#pragma unroll
                    for (int r = 0; r < 4; r++) od[qs][dt][r] *= sf[r];
            }
        }
#pragma unroll
        for (int qs = 0; qs < 2; qs++) {
            float ps[4];
#pragma unroll
            for (int kt = 0; kt < 4; kt++) {
                float p0 = exp2f(sc[qs][kt][0] - m[qs]), p1 = exp2f(sc[qs][kt][1] - m[qs]);
                float p2 = exp2f(sc[qs][kt][2] - m[qs]), p3 = exp2f(sc[qs][kt][3] - m[qs]);
                sc[qs][kt][0] = p0; sc[qs][kt][1] = p1; sc[qs][kt][2] = p2; sc[qs][kt][3] = p3;
                ps[kt] = (p0 + p1) + (p2 + p3);
            }
            float psum = (ps[0] + ps[1]) + (ps[2] + ps[3]);
            psum += __shfl_xor(psum, 16);
            psum += __shfl_xor(psum, 32);
            lsum[qs] += psum;
#pragma unroll
            for (int kt = 0; kt < 4; kt++) {
                half4 ph;
#pragma unroll
                for (int r = 0; r < 4; r++) ph[r] = (_Float16)sc[qs][kt][r];
                *(half4*)(&P[wid][qs * 16 + lr][kt * 16 + lg * 4]) = ph;
            }
        }
        __builtin_amdgcn_s_setprio(1);
#pragma unroll
        for (int ks = 0; ks < 2; ks++) {
            half8 pa0 = *(const half8*)(&P[wid][lr][ks * 32 + lg * 8]);
            half8 pa1 = *(const half8*)(&P[wid][16 + lr][ks * 32 + lg * 8]);
#pragma unroll
            for (int dt = 0; dt < 4; dt++) {
                half8 vb = *(const half8*)(&Vl[cur][(dt * 16 + lr) * 64 + (((ks * 4 + lg) ^ (lr & 7)) * 8)]);
                od[0][dt] = __builtin_amdgcn_mfma_f32_16x16x32_f16(pa0, vb, od[0][dt], 0, 0, 0);
                od[1][dt] = __builtin_amdgcn_mfma_f32_16x16x32_f16(pa1, vb, od[1][dt], 0, 0, 0);
            }
        }
        __builtin_amdgcn_s_setprio(0);
        __syncthreads();
        cur ^= 1;
    }

    _Float16* Ob = Opart + ((size_t)h * NCHUNK + x) * 256 * 64;
#pragma unroll
    for (int qs = 0; qs < 2; qs++) {
        const float inv = 1.0f / lsum[qs];
        float invb[4];
#pragma unroll
        for (int r = 0; r < 4; r++) invb[r] = __shfl(inv, srcb + r);
#pragma unroll
        for (int dt = 0; dt < 4; dt++)
#pragma unroll
            for (int r = 0; r < 4; r++)
                Ob[(size_t)(wid * 32 + qs * 16 + lg * 4 + r) * 64 + dt * 16 + lr] =
                    (_Float16)(od[qs][dt][r] * invb[r]);
    }
    if (lane < 16) {
#pragma unroll
        for (int qs = 0; qs < 2; qs++) {
            float2 v; v.x = m[qs]; v.y = lsum[qs];
            ml[((size_t)h * NCHUNK + x) * 256 + wid * 32 + qs * 16 + lr] = v;
        }
    }
}

// ---------------- chunk combine: at[q][h*64+d] fp16 ----------------
__global__ __launch_bounds__(256) void combine_kernel(
    const _Float16* __restrict__ Opart, const float2* __restrict__ ml,
    _Float16* __restrict__ at, AttnMap map)
{
    const int idx = blockIdx.x * 256 + threadIdx.x;
    const int qrow = idx >> 7;
    const int c8 = (idx & 127) * 8;
    const int h = c8 >> 6, d = c8 & 63;
    const int qt = qrow >> 8;
    const int cb = map.base[qt];
    const int nc = map.base[qt + 1] - cb;
    const int lrow = qrow & 255;

    float M = -1e30f, denom = 0.0f;
    float acc[8];
#pragma unroll
    for (int j = 0; j < 8; j++) acc[j] = 0.0f;
    for (int cc = 0; cc < nc; cc++) {
        const size_t ci = (size_t)h * NCHUNK + cb + cc;
        const float2 mlv = ml[ci * 256 + lrow];
        half8 ov = *(const half8*)(Opart + (ci * 256 + lrow) * 64 + d);
        if (mlv.x > M) {
            const float r = exp2f(M - mlv.x);
            denom = denom * r + mlv.y;
#pragma unroll
            for (int j = 0; j < 8; j++) acc[j] = acc[j] * r + (float)ov[j] * mlv.y;
            M = mlv.x;
        } else {
            const float w = exp2f(mlv.x - M) * mlv.y;
            denom += w;
#pragma unroll
            for (int j = 0; j < 8; j++) acc[j] += (float)ov[j] * w;
        }
    }
    const float inv = 1.0f / denom;
    half8 o;
#pragma unroll
    for (int j = 0; j < 8; j++) o[j] = (_Float16)(acc[j] * inv);
    *(half8*)(at + (size_t)qrow * DMODEL + c8) = o;
}

// ---------------- launch ----------------
extern "C" void kernel_launch(void* const* d_in, const int* in_sizes, int n_in,
                              void* d_out, int out_size, void* d_ws, size_t ws_size,
                              hipStream_t stream) {
    const float* Q  = (const float*)d_in[0];
    const float* K  = (const float*)d_in[1];
    const float* V  = (const float*)d_in[2];
    const float* Wq = (const float*)d_in[3];
    const float* bq = (const float*)d_in[4];
    const float* Wk = (const float*)d_in[5];
    const float* bk = (const float*)d_in[6];
    const float* Wv = (const float*)d_in[7];
    const float* bv = (const float*)d_in[8];
    const float* Wo = (const float*)d_in[9];
    const float* bo = (const float*)d_in[10];

    // 32 MB workspace, liveness-aliased (MB offsets):
    //  0-4  : Vt  (qkv z2 transposed out -> attn)
    //  4-8  : qh  (qkv -> attn)          -> at (combine -> gemm_out)
    //  8-12 : kh  (qkv -> attn)
    // 12-14 : Woh (cvt -> gemm_out)
    // 14-18 : Qh  (cvt -> qkv)  \
    // 18-22 : Kh                 \
    // 22-26 : Vh                  > dead after qkv -> Opart(16MB)@14 + ml(1MB)@30
    // 26-28 : Wqh                /
    // 28-30 : Wkh               /
    // 30-32 : Wvh              /
    char* w = (char*)d_ws;
    const size_t MB = 1 << 20;
    _Float16* Vt  = (_Float16*)(w + 0 * MB);
    _Float16* qh  = (_Float16*)(w + 4 * MB);
    _Float16* kh  = (_Float16*)(w + 8 * MB);
    _Float16* Woh = (_Float16*)(w + 12 * MB);
    _Float16* Qh  = (_Float16*)(w + 14 * MB);
    _Float16* Kh  = (_Float16*)(w + 18 * MB);
    _Float16* Vh  = (_Float16*)(w + 22 * MB);
    _Float16* Wqh = (_Float16*)(w + 26 * MB);
    _Float16* Wkh = (_Float16*)(w + 28 * MB);
    _Float16* Wvh = (_Float16*)(w + 30 * MB);
    _Float16* Opart = (_Float16*)(w + 14 * MB);   // 16 MB exactly
    float2*   ml    = (float2*)(w + 30 * MB);     // 1 MB
    _Float16* at    = qh;

    const size_t SD = (size_t)S_LEN * DMODEL;
    const size_t WD = (size_t)DMODEL * DMODEL;

    CvtArgs ca;
    ca.src[0] = Q;  ca.dst[0] = Qh;  ca.n[0] = (int)SD;
    ca.src[1] = K;  ca.dst[1] = Kh;  ca.n[1] = (int)SD;
    ca.src[2] = V;  ca.dst[2] = Vh;  ca.n[2] = (int)SD;
    ca.src[3] = Wq; ca.dst[3] = Wqh; ca.n[3] = (int)WD;
    ca.src[4] = Wk; ca.dst[4] = Wkh; ca.n[4] = (int)WD;
    ca.src[5] = Wv; ca.dst[5] = Wvh; ca.n[5] = (int)WD;
    ca.src[6] = Wo; ca.dst[6] = Woh; ca.n[6] = (int)WD;
    cvt_kernel<<<dim3(512, 1, 7), 256, 0, stream>>>(ca);

    QKVArgs ga;
    ga.A[0] = Qh; ga.W[0] = Wqh; ga.bias[0] = bq; ga.C[0] = qh; ga.scale[0] = 0.125f * LOG2E;
    ga.A[1] = Kh; ga.W[1] = Wkh; ga.bias[1] = bk; ga.C[1] = kh; ga.scale[1] = 1.0f;
    ga.A[2] = Vh; ga.W[2] = Wvh; ga.bias[2] = bv; ga.C[2] = Vt; ga.scale[2] = 1.0f;
    gemm_qkv<<<dim3(768), 256, 0, stream>>>(ga);

    AttnMap map;
    map.base[0] = 0;
    for (int qt = 0; qt < 8; qt++)
        map.base[qt + 1] = map.base[qt] + (4 * (qt + 1) + CHUNK - 1) / CHUNK;
    // map.base[8] == NCHUNK (32)

    attn_kernel<<<dim3(NCHUNK, NHEADS), 512, 0, stream>>>(qh, kh, Vt, Opart, ml, map);
    combine_kernel<<<dim3(1024), 256, 0, stream>>>(Opart, ml, at, map);
    gemm_out_k<<<dim3(512), 256, 0, stream>>>(at, Woh, bo, (float*)d_out);
}